// Round 7
// baseline (451.885 us; speedup 1.0000x reference)
//
#include <hip/hip_runtime.h>
#include <hip/hip_bf16.h>
#include <hip/hip_fp8.h>

#define N_ROWS 4096
#define IN_DIM 768
#define OUT_DIM 512

// Tiles: 128 rows (A) x 64 cols (B), 256 threads, wave = 64x32 (4x2 frags).
// LDS 24 KB single-buffered -> 3-4 blocks/CU (TLP covers staging drains).
// bf16 LDS rows: 64 elems (128 B), XOR-swizzled 16B chunks (lc^(r&7)).
// fp8 gram: K-permuted rows of 128 B (see l2norm_fp8), b128 reads.

using bf16x8 = __attribute__((ext_vector_type(8))) short;
using f32x4  = __attribute__((ext_vector_type(4))) float;
using i64    = long;
using i64x2  = __attribute__((ext_vector_type(2))) long;

__device__ __constant__ int c_docmap[6] = {0, 1, 0, 2, 1, 2};

__device__ inline unsigned short f2bf(float f) {
    __hip_bfloat16 h = __float2bfloat16(f);
    return reinterpret_cast<unsigned short&>(h);
}
__device__ inline float bf2f(unsigned short u) {
    return __uint_as_float((unsigned int)u << 16);
}
__device__ inline unsigned char f2fp8(float f) {
    __hip_fp8_e4m3 t(f);           // OCP e4m3fn, RNE+sat
    return t.__x;
}

// ---------------- fused prep: conversions + transposes + zero-init ----------------
// seg 0..2: doc->bf16; 3: W1^T; 4: W2^T; 5: zero stats/rowsumsq/rowsum region.
__global__ void prep(const float* __restrict__ d0, const float* __restrict__ d1,
                     const float* __restrict__ d2, const float* __restrict__ W1s,
                     const float* __restrict__ W2s, unsigned short* __restrict__ Xb,
                     unsigned short* __restrict__ W1t, unsigned short* __restrict__ W2t,
                     char* __restrict__ zbase) {
    int seg = blockIdx.y;
    size_t i4 = ((size_t)blockIdx.x * 256 + threadIdx.x) * 4;
    if (seg < 3) {
        const size_t n1 = (size_t)N_ROWS * IN_DIM;
        if (i4 >= n1) return;
        const float* src = (seg == 0) ? d0 : ((seg == 1) ? d1 : d2);
        float4 v = *(const float4*)(src + i4);
        ushort4 o;
        o.x = f2bf(v.x); o.y = f2bf(v.y); o.z = f2bf(v.z); o.w = f2bf(v.w);
        *(ushort4*)(Xb + seg * n1 + i4) = o;
    } else if (seg == 3) {
        const size_t tot = (size_t)6 * IN_DIM * OUT_DIM;
        if (i4 >= tot) return;
        size_t r = i4;
        int z = (int)(r / ((size_t)OUT_DIM * IN_DIM)); r %= (size_t)OUT_DIM * IN_DIM;
        int n = (int)(r / IN_DIM);
        int k = (int)(r % IN_DIM);
        const float* W = W1s + (size_t)z * IN_DIM * OUT_DIM;
        ushort4 o;
        o.x = f2bf(W[(size_t)(k + 0) * OUT_DIM + n]);
        o.y = f2bf(W[(size_t)(k + 1) * OUT_DIM + n]);
        o.z = f2bf(W[(size_t)(k + 2) * OUT_DIM + n]);
        o.w = f2bf(W[(size_t)(k + 3) * OUT_DIM + n]);
        *(ushort4*)(W1t + i4) = o;
    } else if (seg == 4) {
        const size_t tot = (size_t)6 * OUT_DIM * OUT_DIM;
        if (i4 >= tot) return;
        size_t r = i4;
        int z = (int)(r / ((size_t)OUT_DIM * OUT_DIM)); r %= (size_t)OUT_DIM * OUT_DIM;
        int n = (int)(r / OUT_DIM);
        int k = (int)(r % OUT_DIM);
        const float* W = W2s + (size_t)z * OUT_DIM * OUT_DIM;
        ushort4 o;
        o.x = f2bf(W[(size_t)(k + 0) * OUT_DIM + n]);
        o.y = f2bf(W[(size_t)(k + 1) * OUT_DIM + n]);
        o.z = f2bf(W[(size_t)(k + 2) * OUT_DIM + n]);
        o.w = f2bf(W[(size_t)(k + 3) * OUT_DIM + n]);
        *(ushort4*)(W2t + i4) = o;
    } else {
        size_t b = i4 * 4;                      // byte offset, 16B per thread
        if (b < (size_t)(24576 + 98304 + 98304))
            *(float4*)(zbase + b) = (float4){0.f, 0.f, 0.f, 0.f};
    }
}

// ---------------- bf16 staging: A 128 rows, B 64 rows (x 64 cols) ----------------
__device__ inline void stageA_bf(const unsigned short* __restrict__ G, int ld,
                                 int row0, int k0, unsigned short* lds,
                                 int wave, int lane) {
    int rbase = wave * 32;
#pragma unroll
    for (int i = 0; i < 4; ++i) {
        int rs = rbase + i * 8;
        int r  = rs + (lane >> 3);
        int lc = (lane & 7) ^ (r & 7);
        const unsigned short* g = G + (size_t)(row0 + r) * ld + k0 + lc * 8;
        unsigned short* l = lds + rs * 64;
        __builtin_amdgcn_global_load_lds(
            (const __attribute__((address_space(1))) unsigned int*)g,
            (__attribute__((address_space(3))) unsigned int*)l, 16, 0, 0);
    }
}
__device__ inline void stageB_bf(const unsigned short* __restrict__ G, int ld,
                                 int row0, int k0, unsigned short* lds,
                                 int wave, int lane) {
    int rbase = wave * 16;
#pragma unroll
    for (int i = 0; i < 2; ++i) {
        int rs = rbase + i * 8;
        int r  = rs + (lane >> 3);
        int lc = (lane & 7) ^ (r & 7);
        const unsigned short* g = G + (size_t)(row0 + r) * ld + k0 + lc * 8;
        unsigned short* l = lds + rs * 64;
        __builtin_amdgcn_global_load_lds(
            (const __attribute__((address_space(1))) unsigned int*)g,
            (__attribute__((address_space(3))) unsigned int*)l, 16, 0, 0);
    }
}

// bf16 MFMA step: BK=64, wave tile 64x32 (4 mt x 2 nt)
__device__ inline void mfma_step_bf(const unsigned short* As, const unsigned short* Bs,
                                    int wrow, int wcol, int lane15, int quad,
                                    f32x4 acc[4][2]) {
#pragma unroll
    for (int kk = 0; kk < 64; kk += 32) {
        int lcb = (kk >> 3) + quad;
        bf16x8 aF[4], bF[2];
#pragma unroll
        for (int t = 0; t < 4; ++t) {
            int row = wrow + t * 16 + lane15;
            aF[t] = *(const bf16x8*)(As + row * 64 + ((lcb ^ (row & 7)) * 8));
        }
#pragma unroll
        for (int t = 0; t < 2; ++t) {
            int row = wcol + t * 16 + lane15;
            bF[t] = *(const bf16x8*)(Bs + row * 64 + ((lcb ^ (row & 7)) * 8));
        }
#pragma unroll
        for (int mt = 0; mt < 4; ++mt)
#pragma unroll
            for (int nt = 0; nt < 2; ++nt)
                acc[mt][nt] = __builtin_amdgcn_mfma_f32_16x16x32_bf16(aF[mt], bF[nt], acc[mt][nt], 0, 0, 0);
    }
}

// ---------------- GEMM1: X @ W1^T + b1, fused BN-stats, FP32 out ----------------
__global__ __launch_bounds__(256) void gemm1_bn(
    const unsigned short* __restrict__ Xb, const unsigned short* __restrict__ W1t,
    const float* __restrict__ biasAll, float* __restrict__ H,
    float* __restrict__ stats) {
    int z = blockIdx.z;
    const unsigned short* A = Xb + (size_t)c_docmap[z] * N_ROWS * IN_DIM;
    const unsigned short* B = W1t + (size_t)z * OUT_DIM * IN_DIM;
    const float* bz = biasAll + (size_t)z * OUT_DIM;
    float* C = H + (size_t)z * N_ROWS * OUT_DIM;

    int m0 = blockIdx.y * 128, n0 = blockIdx.x * 64;
    int tid = threadIdx.x;
    int wave = tid >> 6, lane = tid & 63;
    int lane15 = lane & 15, quad = lane >> 4;
    int wrow = (wave >> 1) * 64, wcol = (wave & 1) * 32;

    __shared__ unsigned short As[128 * 64];
    __shared__ unsigned short Bs[64 * 64];

    f32x4 acc[4][2];
#pragma unroll
    for (int mt = 0; mt < 4; ++mt)
#pragma unroll
        for (int nt = 0; nt < 2; ++nt)
            acc[mt][nt] = (f32x4){0.f, 0.f, 0.f, 0.f};

    for (int k0 = 0; k0 < IN_DIM; k0 += 64) {
        stageA_bf(A, IN_DIM, m0, k0, As, wave, lane);
        stageB_bf(B, IN_DIM, n0, k0, Bs, wave, lane);
        __syncthreads();
        mfma_step_bf(As, Bs, wrow, wcol, lane15, quad, acc);
        __syncthreads();
    }

    float s1[2] = {0.f, 0.f}, s2[2] = {0.f, 0.f};
#pragma unroll
    for (int nt = 0; nt < 2; ++nt) {
        int col = n0 + wcol + nt * 16 + lane15;
        float bv = bz[col];
#pragma unroll
        for (int mt = 0; mt < 4; ++mt)
#pragma unroll
            for (int r = 0; r < 4; ++r) {
                int row = m0 + wrow + mt * 16 + quad * 4 + r;
                float v = acc[mt][nt][r] + bv;
                C[(size_t)row * OUT_DIM + col] = v;
                s1[nt] += v; s2[nt] += v * v;
            }
    }
#pragma unroll
    for (int nt = 0; nt < 2; ++nt) {
        float a = s1[nt], b = s2[nt];
        a += __shfl_xor(a, 16); a += __shfl_xor(a, 32);
        b += __shfl_xor(b, 16); b += __shfl_xor(b, 32);
        if (quad == 0) {
            int col = n0 + wcol + nt * 16 + lane15;
            atomicAdd(&stats[((size_t)z * OUT_DIM + col) * 2 + 0], a);
            atomicAdd(&stats[((size_t)z * OUT_DIM + col) * 2 + 1], b);
        }
    }
}

// ---------------- BN apply + ReLU: fp32 H -> bf16 Hb ----------------
__global__ void bn_apply(const float* __restrict__ H, unsigned short* __restrict__ Hb,
                         const float* __restrict__ stats, const float* __restrict__ gammas,
                         const float* __restrict__ betas) {
    size_t i4 = ((size_t)blockIdx.x * blockDim.x + threadIdx.x) * 4;
    if (i4 >= (size_t)6 * N_ROWS * OUT_DIM) return;
    int c = (int)(i4 % OUT_DIM);
    int k = (int)(i4 / ((size_t)N_ROWS * OUT_DIM));
    float4 h = *(const float4*)(H + i4);
    float hv[4] = {h.x, h.y, h.z, h.w};
    ushort4 o;
    unsigned short* ov = (unsigned short*)&o;
#pragma unroll
    for (int j = 0; j < 4; ++j) {
        size_t sc = (size_t)k * OUT_DIM + c + j;
        float mu = stats[sc * 2 + 0] * (1.f / N_ROWS);
        float var = stats[sc * 2 + 1] * (1.f / N_ROWS) - mu * mu;
        float v = (hv[j] - mu) * rsqrtf(var + 1e-5f) * gammas[sc] + betas[sc];
        ov[j] = f2bf(fmaxf(v, 0.f));
    }
    *(ushort4*)(Hb + i4) = o;
}

// ---------------- GEMM2: Hb @ W2^T + b2, fused row-sumsq, BF16 out ----------------
__global__ __launch_bounds__(256) void gemm2_norm(
    const unsigned short* __restrict__ Hb, const unsigned short* __restrict__ W2t,
    const float* __restrict__ biasAll, unsigned short* __restrict__ O,
    float* __restrict__ rowsumsq) {
    int z = blockIdx.z;
    const unsigned short* A = Hb + (size_t)z * N_ROWS * OUT_DIM;
    const unsigned short* B = W2t + (size_t)z * OUT_DIM * OUT_DIM;
    const float* bz = biasAll + (size_t)z * OUT_DIM;
    unsigned short* C = O + (size_t)z * N_ROWS * OUT_DIM;
    float* rq = rowsumsq + (size_t)z * N_ROWS;

    int m0 = blockIdx.y * 128, n0 = blockIdx.x * 64;
    int tid = threadIdx.x;
    int wave = tid >> 6, lane = tid & 63;
    int lane15 = lane & 15, quad = lane >> 4;
    int wrow = (wave >> 1) * 64, wcol = (wave & 1) * 32;

    __shared__ unsigned short As[128 * 64];
    __shared__ unsigned short Bs[64 * 64];

    f32x4 acc[4][2];
#pragma unroll
    for (int mt = 0; mt < 4; ++mt)
#pragma unroll
        for (int nt = 0; nt < 2; ++nt)
            acc[mt][nt] = (f32x4){0.f, 0.f, 0.f, 0.f};

    for (int k0 = 0; k0 < OUT_DIM; k0 += 64) {
        stageA_bf(A, OUT_DIM, m0, k0, As, wave, lane);
        stageB_bf(B, OUT_DIM, n0, k0, Bs, wave, lane);
        __syncthreads();
        mfma_step_bf(As, Bs, wrow, wcol, lane15, quad, acc);
        __syncthreads();
    }

    float rs[16];
#pragma unroll
    for (int j = 0; j < 16; ++j) rs[j] = 0.f;
#pragma unroll
    for (int nt = 0; nt < 2; ++nt) {
        int col = n0 + wcol + nt * 16 + lane15;
        float bv = bz[col];
#pragma unroll
        for (int mt = 0; mt < 4; ++mt)
#pragma unroll
            for (int r = 0; r < 4; ++r) {
                int row = m0 + wrow + mt * 16 + quad * 4 + r;
                float v = acc[mt][nt][r] + bv;
                C[(size_t)row * OUT_DIM + col] = f2bf(v);
                rs[mt * 4 + r] += v * v;
            }
    }
#pragma unroll
    for (int j = 0; j < 16; ++j) {
        float v = rs[j];
        v += __shfl_xor(v, 1); v += __shfl_xor(v, 2);
        v += __shfl_xor(v, 4); v += __shfl_xor(v, 8);
        if (lane15 == 0) {
            int row = m0 + wrow + (j >> 2) * 16 + quad * 4 + (j & 3);
            atomicAdd(&rq[row], v);
        }
    }
}

// ---------------- row L2 norm: bf16 O -> fp8 e4m3, K-PERMUTED layout ----------------
__global__ __launch_bounds__(256) void l2norm_fp8(const unsigned short* __restrict__ O,
                                                  const float* __restrict__ rowsumsq,
                                                  unsigned char* __restrict__ A) {
    int wave = threadIdx.x >> 6, lane = threadIdx.x & 63;
    int row = blockIdx.x * 4 + wave;
    float sc = 1.f / fmaxf(sqrtf(rowsumsq[row]), 1e-12f);
    const unsigned short* Op = O + (size_t)row * OUT_DIM + lane * 8;
    uint4 u = *(const uint4*)Op;
    unsigned int w[4] = {u.x, u.y, u.z, u.w};
    unsigned long long pk = 0;
#pragma unroll
    for (int j = 0; j < 8; ++j) {
        unsigned short us = (j & 1) ? (unsigned short)(w[j >> 1] >> 16)
                                    : (unsigned short)(w[j >> 1] & 0xffff);
        pk |= (unsigned long long)f2fp8(bf2f(us) * sc) << (8 * j);
    }
    int phys = ((lane >> 4) << 7) + ((lane & 3) << 5) + (((lane >> 2) & 3) << 3);
    *(unsigned long long*)(A + (size_t)row * OUT_DIM + phys) = pk;
}

// ---------------- fp8 staging: A 128 rows, B 64 rows (x 128 B) ----------------
__device__ inline void stageA_fp8(const unsigned char* __restrict__ G, int ld,
                                  int row0, int k0, unsigned char* lds,
                                  int wave, int lane) {
    int rbase = wave * 32;
#pragma unroll
    for (int i = 0; i < 4; ++i) {
        int rs = rbase + i * 8;
        int r  = rs + (lane >> 3);
        int lc = (lane & 7) ^ (r & 7);
        const unsigned char* g = G + (size_t)(row0 + r) * ld + k0 + lc * 16;
        unsigned char* l = lds + rs * 128;
        __builtin_amdgcn_global_load_lds(
            (const __attribute__((address_space(1))) unsigned int*)g,
            (__attribute__((address_space(3))) unsigned int*)l, 16, 0, 0);
    }
}
__device__ inline void stageB_fp8(const unsigned char* __restrict__ G, int ld,
                                  int row0, int k0, unsigned char* lds,
                                  int wave, int lane) {
    int rbase = wave * 16;
#pragma unroll
    for (int i = 0; i < 2; ++i) {
        int rs = rbase + i * 8;
        int r  = rs + (lane >> 3);
        int lc = (lane & 7) ^ (r & 7);
        const unsigned char* g = G + (size_t)(row0 + r) * ld + k0 + lc * 16;
        unsigned char* l = lds + rs * 128;
        __builtin_amdgcn_global_load_lds(
            (const __attribute__((address_space(1))) unsigned int*)g,
            (__attribute__((address_space(3))) unsigned int*)l, 16, 0, 0);
    }
}

// ---------------- symmetric fp8 Gram: 128x64 tiles, masked upper-tri ----------------
// Cm = [o1;o2]: [8192][512] fp8 e4m3 (K-permuted), rows L2-normalized.
// Row-tiles I of 128 (64), col-tiles J of 64 (128), J >= 2I: 4160 blocks/pair.
// Mask per element: grow<gcol -> exp(2s) to rowsum[grow] AND rowsum[gcol];
// grow==gcol excluded (so loss denom = rowsum directly); cross diag -> crossdot.
__global__ __launch_bounds__(256) void gram_kernel(const unsigned char* __restrict__ Abase,
                                                   float* __restrict__ rowsum,
                                                   float* __restrict__ crossdot) {
    int p = blockIdx.z;
    const unsigned char* Cm = Abase + (size_t)p * 2 * N_ROWS * OUT_DIM;

    int idx = blockIdx.x, I = 0;
    while (idx >= 128 - 2 * I) { idx -= 128 - 2 * I; ++I; }
    int J = 2 * I + idx;
    int m0 = I * 128, n0 = J * 64;

    int tid = threadIdx.x;
    int wave = tid >> 6, lane = tid & 63;
    int lane15 = lane & 15, quad = lane >> 4;
    int wrow = (wave >> 1) * 64, wcol = (wave & 1) * 32;

    __shared__ unsigned char As[128 * 128];   // 16 KB
    __shared__ unsigned char Bs[64 * 128];    //  8 KB

    f32x4 acc[4][2];
#pragma unroll
    for (int mt = 0; mt < 4; ++mt)
#pragma unroll
        for (int nt = 0; nt < 2; ++nt)
            acc[mt][nt] = (f32x4){0.f, 0.f, 0.f, 0.f};

    for (int k0 = 0; k0 < OUT_DIM; k0 += 128) {
        stageA_fp8(Cm, OUT_DIM, m0, k0, As, wave, lane);
        stageB_fp8(Cm, OUT_DIM, n0, k0, Bs, wave, lane);
        __syncthreads();
#pragma unroll
        for (int t2 = 0; t2 < 2; ++t2) {
            int c16 = 2 * quad + t2;
            i64x2 aF[4], bF[2];
#pragma unroll
            for (int t = 0; t < 4; ++t) {
                int row = wrow + t * 16 + lane15;
                aF[t] = *(const i64x2*)(As + row * 128 + ((c16 ^ (row & 7)) << 4));
            }
#pragma unroll
            for (int t = 0; t < 2; ++t) {
                int row = wcol + t * 16 + lane15;
                bF[t] = *(const i64x2*)(Bs + row * 128 + ((c16 ^ (row & 7)) << 4));
            }
#pragma unroll
            for (int half = 0; half < 2; ++half)
#pragma unroll
                for (int mt = 0; mt < 4; ++mt)
#pragma unroll
                    for (int nt = 0; nt < 2; ++nt)
                        acc[mt][nt] = __builtin_amdgcn_mfma_f32_16x16x32_fp8_fp8(
                            aF[mt][half], bF[nt][half], acc[mt][nt], 0, 0, 0);
        }
        __syncthreads();
    }

    float* cdp = crossdot + (size_t)p * 2 * N_ROWS;
    float* rp  = rowsum  + (size_t)p * 2 * N_ROWS;

    float rs[16];
    float cs[2] = {0.f, 0.f};
#pragma unroll
    for (int j = 0; j < 16; ++j) rs[j] = 0.f;

#pragma unroll
    for (int mt = 0; mt < 4; ++mt)
#pragma unroll
        for (int nt = 0; nt < 2; ++nt) {
            int gcol = n0 + wcol + nt * 16 + lane15;
#pragma unroll
            for (int r = 0; r < 4; ++r) {
                int grow = m0 + wrow + mt * 16 + quad * 4 + r;
                float s = acc[mt][nt][r];
                if (grow < gcol) {
                    float e = __expf(2.f * s);
                    rs[mt * 4 + r] += e;
                    cs[nt] += e;
                }
                if (gcol == grow + N_ROWS) { cdp[grow] = s; cdp[gcol] = s; }
            }
        }

#pragma unroll
    for (int j = 0; j < 16; ++j) {
        float v = rs[j];
        v += __shfl_xor(v, 1); v += __shfl_xor(v, 2);
        v += __shfl_xor(v, 4); v += __shfl_xor(v, 8);
        rs[j] = v;
    }
    if (lane15 == 0) {
#pragma unroll
        for (int j = 0; j < 16; ++j) {
            int grow = m0 + wrow + (j >> 2) * 16 + quad * 4 + (j & 3);
            atomicAdd(&rp[grow], rs[j]);
        }
    }

#pragma unroll
    for (int n = 0; n < 2; ++n) {
        float v = cs[n];
        v += __shfl_xor(v, 16); v += __shfl_xor(v, 32);
        cs[n] = v;
    }
    if (quad == 0) {
#pragma unroll
        for (int n = 0; n < 2; ++n) {
            int gcol = n0 + wcol + n * 16 + lane15;
            atomicAdd(&rp[gcol], cs[n]);
        }
    }
}

// ---------------- final loss reduction ----------------
__global__ void loss_kernel(const float* __restrict__ rowsum,
                            const float* __restrict__ crossdot, float* __restrict__ out) {
    __shared__ float red[256];
    float acc = 0.f;
    for (int i = threadIdx.x; i < 3 * 2 * N_ROWS; i += 256) {
        // diagonal never accumulated -> denom is rowsum directly
        acc += logf(rowsum[i]) - 2.f * crossdot[i];
    }
    red[threadIdx.x] = acc;
    __syncthreads();
    for (int s = 128; s > 0; s >>= 1) {
        if (threadIdx.x < s) red[threadIdx.x] += red[threadIdx.x + s];
        __syncthreads();
    }
    if (threadIdx.x == 0) out[0] = red[0] * (1.f / 24576.f);
}

// ---------------- launch ----------------
extern "C" void kernel_launch(void* const* d_in, const int* in_sizes, int n_in,
                              void* d_out, int out_size, void* d_ws, size_t ws_size,
                              hipStream_t stream) {
    const float* doc0   = (const float*)d_in[0];
    const float* doc1   = (const float*)d_in[1];
    const float* doc2   = (const float*)d_in[2];
    const float* W1s    = (const float*)d_in[3];
    const float* b1s    = (const float*)d_in[4];
    const float* gammas = (const float*)d_in[5];
    const float* betas  = (const float*)d_in[6];
    const float* W2s    = (const float*)d_in[7];
    const float* b2s    = (const float*)d_in[8];
    float* out = (float*)d_out;

    char* base = (char*)d_ws;
    size_t off = 0;
    auto alloc = [&](size_t bytes) -> char* {
        char* r = base + off;
        off += (bytes + 255) & ~(size_t)255;
        return r;
    };

    // Xb dead after gemm1 -> Abuf aliases it. H fp32 dead after bn_apply -> O bf16 aliases it.
    unsigned short* Xb   = (unsigned short*)alloc((size_t)3 * N_ROWS * IN_DIM * 2);
    unsigned short* W1t  = (unsigned short*)alloc((size_t)6 * OUT_DIM * IN_DIM * 2);
    unsigned short* W2t  = (unsigned short*)alloc((size_t)6 * OUT_DIM * OUT_DIM * 2);
    float*          H    = (float*)         alloc((size_t)6 * N_ROWS * OUT_DIM * 4);
    unsigned short* Hb   = (unsigned short*)alloc((size_t)6 * N_ROWS * OUT_DIM * 2);
    unsigned char*  Abuf = (unsigned char*)Xb;
    unsigned short* O    = (unsigned short*)H;
    char* zbase = alloc(24576 + 98304 + 98304);
    float* stats    = (float*)zbase;
    float* rowsumsq = (float*)(zbase + 24576);
    float* rowsum   = (float*)(zbase + 24576 + 98304);
    float* cdot     = (float*)alloc((size_t)3 * 2 * N_ROWS * 4);

    if (ws_size < off) return;

    // prep: conversions + transposes + zero-init (seg 5), no separate memset
    prep<<<dim3(3072, 6), 256, 0, stream>>>(doc0, doc1, doc2, W1s, W2s, Xb, W1t, W2t, zbase);

    gemm1_bn<<<dim3(OUT_DIM / 64, N_ROWS / 128, 6), 256, 0, stream>>>(Xb, W1t, b1s, H, stats);

    bn_apply<<<(int)(((size_t)6 * N_ROWS * OUT_DIM / 4 + 255) / 256), 256, 0, stream>>>(
        H, Hb, stats, gammas, betas);

    gemm2_norm<<<dim3(OUT_DIM / 64, N_ROWS / 128, 6), 256, 0, stream>>>(Hb, W2t, b2s, O, rowsumsq);

    l2norm_fp8<<<6 * N_ROWS / 4, 256, 0, stream>>>(O, rowsumsq, Abuf);

    // masked symmetric gram: sum_{I=0}^{63}(128-2I) = 4160 blocks per pair
    gram_kernel<<<dim3(4160, 1, 3), 256, 0, stream>>>(Abuf, rowsum, cdot);

    loss_kernel<<<1, 256, 0, stream>>>(rowsum, cdot, out);
}

// Round 8
// 377.893 us; speedup vs baseline: 1.1958x; 1.1958x over previous
//
#include <hip/hip_runtime.h>
#include <hip/hip_bf16.h>
#include <hip/hip_fp8.h>

#define N_ROWS 4096
#define IN_DIM 768
#define OUT_DIM 512

#define BM 128
#define BN 128
#define BK 64
// bf16 GEMMs (128x128 tiles, 256 thr): LDS rows 64 elems (128 B), XOR-swizzled
// 16B chunks (lc^(r&7)); 0 conflicts measured (R2-R6).
// Gram (fp8): NO LDS. Abuf stored fragment-major by l2norm_fp8:
//   byte addr = ((gt*8 + kh)*64 + lane)*16,  gt = row>>4, kh = K-64B-chunk pair;
//   lane's 16 B = MFMA A-frags for kf=2kh (low 8B) and 2kh+1 (high 8B),
//   element (row = gt*16 + (lane&15), k = kf*32 + (lane>>4)*8 + j).
// Gram K-loop: coalesced global_load_dwordx4 -> MFMA, no barriers at all.

using bf16x8 = __attribute__((ext_vector_type(8))) short;
using f32x4  = __attribute__((ext_vector_type(4))) float;
using i64    = long;
using i64x2  = __attribute__((ext_vector_type(2))) long;

__device__ __constant__ int c_docmap[6] = {0, 1, 0, 2, 1, 2};

__device__ inline unsigned short f2bf(float f) {
    __hip_bfloat16 h = __float2bfloat16(f);
    return reinterpret_cast<unsigned short&>(h);
}
__device__ inline float bf2f(unsigned short u) {
    return __uint_as_float((unsigned int)u << 16);
}
__device__ inline unsigned char f2fp8(float f) {
    __hip_fp8_e4m3 t(f);           // OCP e4m3fn, RNE+sat
    return t.__x;
}

// ---------------- fused prep: conversions + transposes + zero-init ----------------
__global__ void prep(const float* __restrict__ d0, const float* __restrict__ d1,
                     const float* __restrict__ d2, const float* __restrict__ W1s,
                     const float* __restrict__ W2s, unsigned short* __restrict__ Xb,
                     unsigned short* __restrict__ W1t, unsigned short* __restrict__ W2t,
                     char* __restrict__ zbase) {
    int seg = blockIdx.y;
    size_t i4 = ((size_t)blockIdx.x * 256 + threadIdx.x) * 4;
    if (seg < 3) {
        const size_t n1 = (size_t)N_ROWS * IN_DIM;
        if (i4 >= n1) return;
        const float* src = (seg == 0) ? d0 : ((seg == 1) ? d1 : d2);
        float4 v = *(const float4*)(src + i4);
        ushort4 o;
        o.x = f2bf(v.x); o.y = f2bf(v.y); o.z = f2bf(v.z); o.w = f2bf(v.w);
        *(ushort4*)(Xb + seg * n1 + i4) = o;
    } else if (seg == 3) {
        const size_t tot = (size_t)6 * IN_DIM * OUT_DIM;
        if (i4 >= tot) return;
        size_t r = i4;
        int z = (int)(r / ((size_t)OUT_DIM * IN_DIM)); r %= (size_t)OUT_DIM * IN_DIM;
        int n = (int)(r / IN_DIM);
        int k = (int)(r % IN_DIM);
        const float* W = W1s + (size_t)z * IN_DIM * OUT_DIM;
        ushort4 o;
        o.x = f2bf(W[(size_t)(k + 0) * OUT_DIM + n]);
        o.y = f2bf(W[(size_t)(k + 1) * OUT_DIM + n]);
        o.z = f2bf(W[(size_t)(k + 2) * OUT_DIM + n]);
        o.w = f2bf(W[(size_t)(k + 3) * OUT_DIM + n]);
        *(ushort4*)(W1t + i4) = o;
    } else if (seg == 4) {
        const size_t tot = (size_t)6 * OUT_DIM * OUT_DIM;
        if (i4 >= tot) return;
        size_t r = i4;
        int z = (int)(r / ((size_t)OUT_DIM * OUT_DIM)); r %= (size_t)OUT_DIM * OUT_DIM;
        int n = (int)(r / OUT_DIM);
        int k = (int)(r % OUT_DIM);
        const float* W = W2s + (size_t)z * OUT_DIM * OUT_DIM;
        ushort4 o;
        o.x = f2bf(W[(size_t)(k + 0) * OUT_DIM + n]);
        o.y = f2bf(W[(size_t)(k + 1) * OUT_DIM + n]);
        o.z = f2bf(W[(size_t)(k + 2) * OUT_DIM + n]);
        o.w = f2bf(W[(size_t)(k + 3) * OUT_DIM + n]);
        *(ushort4*)(W2t + i4) = o;
    } else {
        size_t b = i4 * 4;
        if (b < (size_t)(24576 + 98304 + 98304))
            *(float4*)(zbase + b) = (float4){0.f, 0.f, 0.f, 0.f};
    }
}

// ---------------- bf16 staging (128 rows x 64 cols, 4 waves) ----------------
__device__ inline void stage_tile_async(const unsigned short* __restrict__ G, int ld,
                                        int row0, int k0, unsigned short* lds,
                                        int wave, int lane) {
    int rbase = wave * 32;
#pragma unroll
    for (int i = 0; i < 4; ++i) {
        int rs = rbase + i * 8;
        int r  = rs + (lane >> 3);
        int lc = (lane & 7) ^ (r & 7);
        const unsigned short* g = G + (size_t)(row0 + r) * ld + k0 + lc * 8;
        unsigned short* l = lds + rs * 64;
        __builtin_amdgcn_global_load_lds(
            (const __attribute__((address_space(1))) unsigned int*)g,
            (__attribute__((address_space(3))) unsigned int*)l, 16, 0, 0);
    }
}

__device__ inline void mfma_step_swz(const unsigned short* As, const unsigned short* Bs,
                                     int wrow, int wcol, int lane15, int quad,
                                     f32x4 acc[4][4]) {
#pragma unroll
    for (int kk = 0; kk < BK; kk += 32) {
        int lcb = (kk >> 3) + quad;
        bf16x8 aF[4], bF[4];
#pragma unroll
        for (int t = 0; t < 4; ++t) {
            int row = wrow + t * 16 + lane15;
            aF[t] = *(const bf16x8*)(As + row * 64 + ((lcb ^ (row & 7)) * 8));
        }
#pragma unroll
        for (int t = 0; t < 4; ++t) {
            int row = wcol + t * 16 + lane15;
            bF[t] = *(const bf16x8*)(Bs + row * 64 + ((lcb ^ (row & 7)) * 8));
        }
#pragma unroll
        for (int mt = 0; mt < 4; ++mt)
#pragma unroll
            for (int nt = 0; nt < 4; ++nt)
                acc[mt][nt] = __builtin_amdgcn_mfma_f32_16x16x32_bf16(aF[mt], bF[nt], acc[mt][nt], 0, 0, 0);
    }
}

// ---------------- GEMM1: X @ W1^T + b1, fused BN-stats, FP32 out ----------------
__global__ __launch_bounds__(256) void gemm1_bn(
    const unsigned short* __restrict__ Xb, const unsigned short* __restrict__ W1t,
    const float* __restrict__ biasAll, float* __restrict__ H,
    float* __restrict__ stats) {
    int z = blockIdx.z;
    const unsigned short* A = Xb + (size_t)c_docmap[z] * N_ROWS * IN_DIM;
    const unsigned short* B = W1t + (size_t)z * OUT_DIM * IN_DIM;
    const float* bz = biasAll + (size_t)z * OUT_DIM;
    float* C = H + (size_t)z * N_ROWS * OUT_DIM;

    int m0 = blockIdx.y * BM, n0 = blockIdx.x * BN;
    int tid = threadIdx.x;
    int wave = tid >> 6, lane = tid & 63;
    int lane15 = lane & 15, quad = lane >> 4;
    int wrow = (wave >> 1) * 64, wcol = (wave & 1) * 64;

    __shared__ unsigned short As[BM * 64];
    __shared__ unsigned short Bs[BN * 64];

    f32x4 acc[4][4];
#pragma unroll
    for (int mt = 0; mt < 4; ++mt)
#pragma unroll
        for (int nt = 0; nt < 4; ++nt)
            acc[mt][nt] = (f32x4){0.f, 0.f, 0.f, 0.f};

    for (int k0 = 0; k0 < IN_DIM; k0 += BK) {
        stage_tile_async(A, IN_DIM, m0, k0, As, wave, lane);
        stage_tile_async(B, IN_DIM, n0, k0, Bs, wave, lane);
        __syncthreads();
        mfma_step_swz(As, Bs, wrow, wcol, lane15, quad, acc);
        __syncthreads();
    }

    float s1[4] = {0.f, 0.f, 0.f, 0.f}, s2[4] = {0.f, 0.f, 0.f, 0.f};
#pragma unroll
    for (int nt = 0; nt < 4; ++nt) {
        int col = n0 + wcol + nt * 16 + lane15;
        float bv = bz[col];
#pragma unroll
        for (int mt = 0; mt < 4; ++mt)
#pragma unroll
            for (int r = 0; r < 4; ++r) {
                int row = m0 + wrow + mt * 16 + quad * 4 + r;
                float v = acc[mt][nt][r] + bv;
                C[(size_t)row * OUT_DIM + col] = v;
                s1[nt] += v; s2[nt] += v * v;
            }
    }
#pragma unroll
    for (int nt = 0; nt < 4; ++nt) {
        float a = s1[nt], b = s2[nt];
        a += __shfl_xor(a, 16); a += __shfl_xor(a, 32);
        b += __shfl_xor(b, 16); b += __shfl_xor(b, 32);
        if (quad == 0) {
            int col = n0 + wcol + nt * 16 + lane15;
            atomicAdd(&stats[((size_t)z * OUT_DIM + col) * 2 + 0], a);
            atomicAdd(&stats[((size_t)z * OUT_DIM + col) * 2 + 1], b);
        }
    }
}

// ---------------- BN apply + ReLU: fp32 H -> bf16 Hb ----------------
__global__ void bn_apply(const float* __restrict__ H, unsigned short* __restrict__ Hb,
                         const float* __restrict__ stats, const float* __restrict__ gammas,
                         const float* __restrict__ betas) {
    size_t i4 = ((size_t)blockIdx.x * blockDim.x + threadIdx.x) * 4;
    if (i4 >= (size_t)6 * N_ROWS * OUT_DIM) return;
    int c = (int)(i4 % OUT_DIM);
    int k = (int)(i4 / ((size_t)N_ROWS * OUT_DIM));
    float4 h = *(const float4*)(H + i4);
    float hv[4] = {h.x, h.y, h.z, h.w};
    ushort4 o;
    unsigned short* ov = (unsigned short*)&o;
#pragma unroll
    for (int j = 0; j < 4; ++j) {
        size_t sc = (size_t)k * OUT_DIM + c + j;
        float mu = stats[sc * 2 + 0] * (1.f / N_ROWS);
        float var = stats[sc * 2 + 1] * (1.f / N_ROWS) - mu * mu;
        float v = (hv[j] - mu) * rsqrtf(var + 1e-5f) * gammas[sc] + betas[sc];
        ov[j] = f2bf(fmaxf(v, 0.f));
    }
    *(ushort4*)(Hb + i4) = o;
}

// ---------------- GEMM2: Hb @ W2^T + b2, fused row-sumsq, BF16 out ----------------
__global__ __launch_bounds__(256) void gemm2_norm(
    const unsigned short* __restrict__ Hb, const unsigned short* __restrict__ W2t,
    const float* __restrict__ biasAll, unsigned short* __restrict__ O,
    float* __restrict__ rowsumsq) {
    int z = blockIdx.z;
    const unsigned short* A = Hb + (size_t)z * N_ROWS * OUT_DIM;
    const unsigned short* B = W2t + (size_t)z * OUT_DIM * OUT_DIM;
    const float* bz = biasAll + (size_t)z * OUT_DIM;
    unsigned short* C = O + (size_t)z * N_ROWS * OUT_DIM;
    float* rq = rowsumsq + (size_t)z * N_ROWS;

    int m0 = blockIdx.y * BM, n0 = blockIdx.x * BN;
    int tid = threadIdx.x;
    int wave = tid >> 6, lane = tid & 63;
    int lane15 = lane & 15, quad = lane >> 4;
    int wrow = (wave >> 1) * 64, wcol = (wave & 1) * 64;

    __shared__ unsigned short As[BM * 64];
    __shared__ unsigned short Bs[BN * 64];

    f32x4 acc[4][4];
#pragma unroll
    for (int mt = 0; mt < 4; ++mt)
#pragma unroll
        for (int nt = 0; nt < 4; ++nt)
            acc[mt][nt] = (f32x4){0.f, 0.f, 0.f, 0.f};

    for (int k0 = 0; k0 < OUT_DIM; k0 += BK) {
        stage_tile_async(A, OUT_DIM, m0, k0, As, wave, lane);
        stage_tile_async(B, OUT_DIM, n0, k0, Bs, wave, lane);
        __syncthreads();
        mfma_step_swz(As, Bs, wrow, wcol, lane15, quad, acc);
        __syncthreads();
    }

    float rs[16];
#pragma unroll
    for (int j = 0; j < 16; ++j) rs[j] = 0.f;
#pragma unroll
    for (int nt = 0; nt < 4; ++nt) {
        int col = n0 + wcol + nt * 16 + lane15;
        float bv = bz[col];
#pragma unroll
        for (int mt = 0; mt < 4; ++mt)
#pragma unroll
            for (int r = 0; r < 4; ++r) {
                int row = m0 + wrow + mt * 16 + quad * 4 + r;
                float v = acc[mt][nt][r] + bv;
                C[(size_t)row * OUT_DIM + col] = f2bf(v);
                rs[mt * 4 + r] += v * v;
            }
    }
#pragma unroll
    for (int j = 0; j < 16; ++j) {
        float v = rs[j];
        v += __shfl_xor(v, 1); v += __shfl_xor(v, 2);
        v += __shfl_xor(v, 4); v += __shfl_xor(v, 8);
        if (lane15 == 0) {
            int row = m0 + wrow + (j >> 2) * 16 + quad * 4 + (j & 3);
            atomicAdd(&rq[row], v);
        }
    }
}

// ---------------- row L2 norm: bf16 O -> fp8 e4m3, FRAGMENT-MAJOR layout ----------------
// Block gt handles 16 rows. Wave w covers kh = 2w, 2w+1. Lane writes 16 B at
// ((gt*8+kh)*64+lane)*16: halves = MFMA frags for kf=2kh, 2kh+1 of
// element (row = gt*16 + (lane&15), k = kf*32 + (lane>>4)*8 + j).
__global__ __launch_bounds__(256) void l2norm_fp8(const unsigned short* __restrict__ O,
                                                  const float* __restrict__ rowsumsq,
                                                  unsigned char* __restrict__ A) {
    int gt = blockIdx.x;                  // 0..1535
    int wave = threadIdx.x >> 6, lane = threadIdx.x & 63;
    int lane15 = lane & 15, quad = lane >> 4;
    int row = gt * 16 + lane15;
    float sc = 1.f / fmaxf(sqrtf(rowsumsq[row]), 1e-12f);
    const unsigned short* Op = O + (size_t)row * OUT_DIM + quad * 8;
#pragma unroll
    for (int t = 0; t < 2; ++t) {
        int kh = wave * 2 + t;
        unsigned long long pk[2];
#pragma unroll
        for (int half = 0; half < 2; ++half) {
            int kf = kh * 2 + half;
            uint4 u = *(const uint4*)(Op + kf * 32);
            unsigned int w[4] = {u.x, u.y, u.z, u.w};
            unsigned long long v = 0;
#pragma unroll
            for (int j = 0; j < 8; ++j) {
                unsigned short us = (j & 1) ? (unsigned short)(w[j >> 1] >> 16)
                                            : (unsigned short)(w[j >> 1] & 0xffff);
                v |= (unsigned long long)f2fp8(bf2f(us) * sc) << (8 * j);
            }
            pk[half] = v;
        }
        i64x2 st; st[0] = (i64)pk[0]; st[1] = (i64)pk[1];
        *(i64x2*)(A + ((size_t)(gt * 8 + kh) * 64 + lane) * 16) = st;
    }
}

// ---------------- barrier-free fp8 Gram: fragment-direct loads ----------------
// Cm = [o1;o2] per pair: 512 row-tiles (gt) x 8 kh x 64 lanes x 16 B.
// 128x128 output tiles, I<=J (2080 blocks/pair). Uniform masking: grow<gcol
// contributes exp(2s) to rowsum[grow] (row) AND rowsum[gcol] (col); diag
// excluded; cross diagonal (gcol==grow+4096) -> crossdot.
__global__ __launch_bounds__(256) void gram_kernel(const unsigned char* __restrict__ Abase,
                                                   float* __restrict__ rowsum,
                                                   float* __restrict__ crossdot) {
    int p = blockIdx.z;
    const unsigned char* Cm = Abase + (size_t)p * 2 * N_ROWS * OUT_DIM;

    int idx = blockIdx.x, I = 0;
    while (idx >= 64 - I) { idx -= 64 - I; ++I; }
    int J = I + idx;
    int m0 = I * 128, n0 = J * 128;

    int tid = threadIdx.x;
    int wave = tid >> 6, lane = tid & 63;
    int lane15 = lane & 15, quad = lane >> 4;
    int wrow = (wave >> 1) * 64, wcol = (wave & 1) * 64;

    const unsigned char* pa[4];
    const unsigned char* pb[4];
#pragma unroll
    for (int t = 0; t < 4; ++t) {
        pa[t] = Cm + ((size_t)((m0 + wrow) >> 4) + t) * 8192 + (size_t)lane * 16;
        pb[t] = Cm + ((size_t)((n0 + wcol) >> 4) + t) * 8192 + (size_t)lane * 16;
    }

    f32x4 acc[4][4];
#pragma unroll
    for (int mt = 0; mt < 4; ++mt)
#pragma unroll
        for (int nt = 0; nt < 4; ++nt)
            acc[mt][nt] = (f32x4){0.f, 0.f, 0.f, 0.f};

    i64x2 aC[4], bC[4], aN[4], bN[4];
#pragma unroll
    for (int t = 0; t < 4; ++t) {
        aC[t] = *(const i64x2*)(pa[t]);
        bC[t] = *(const i64x2*)(pb[t]);
    }

#pragma unroll
    for (int kh = 0; kh < 8; ++kh) {
        if (kh < 7) {
#pragma unroll
            for (int t = 0; t < 4; ++t) {
                aN[t] = *(const i64x2*)(pa[t] + (kh + 1) * 1024);
                bN[t] = *(const i64x2*)(pb[t] + (kh + 1) * 1024);
            }
        }
#pragma unroll
        for (int half = 0; half < 2; ++half)
#pragma unroll
            for (int mt = 0; mt < 4; ++mt)
#pragma unroll
                for (int nt = 0; nt < 4; ++nt)
                    acc[mt][nt] = __builtin_amdgcn_mfma_f32_16x16x32_fp8_fp8(
                        aC[mt][half], bC[nt][half], acc[mt][nt], 0, 0, 0);
#pragma unroll
        for (int t = 0; t < 4; ++t) { aC[t] = aN[t]; bC[t] = bN[t]; }
    }

    float* cdp = crossdot + (size_t)p * 2 * N_ROWS;
    float* rp  = rowsum  + (size_t)p * 2 * N_ROWS;

    float rs[16];
    float cs[4] = {0.f, 0.f, 0.f, 0.f};
#pragma unroll
    for (int j = 0; j < 16; ++j) rs[j] = 0.f;

#pragma unroll
    for (int mt = 0; mt < 4; ++mt)
#pragma unroll
        for (int nt = 0; nt < 4; ++nt) {
            int gcol = n0 + wcol + nt * 16 + lane15;
#pragma unroll
            for (int r = 0; r < 4; ++r) {
                int grow = m0 + wrow + mt * 16 + quad * 4 + r;
                float s = acc[mt][nt][r];
                if (grow < gcol) {
                    float e = __expf(2.f * s);
                    rs[mt * 4 + r] += e;
                    cs[nt] += e;
                }
                if (gcol == grow + N_ROWS) { cdp[grow] = s; cdp[gcol] = s; }
            }
        }

#pragma unroll
    for (int j = 0; j < 16; ++j) {
        float v = rs[j];
        v += __shfl_xor(v, 1); v += __shfl_xor(v, 2);
        v += __shfl_xor(v, 4); v += __shfl_xor(v, 8);
        rs[j] = v;
    }
    if (lane15 == 0) {
#pragma unroll
        for (int j = 0; j < 16; ++j) {
            int grow = m0 + wrow + (j >> 2) * 16 + quad * 4 + (j & 3);
            atomicAdd(&rp[grow], rs[j]);
        }
    }

#pragma unroll
    for (int n = 0; n < 4; ++n) {
        float v = cs[n];
        v += __shfl_xor(v, 16); v += __shfl_xor(v, 32);
        cs[n] = v;
    }
    if (quad == 0) {
#pragma unroll
        for (int n = 0; n < 4; ++n) {
            int gcol = n0 + wcol + n * 16 + lane15;
            atomicAdd(&rp[gcol], cs[n]);
        }
    }
}

// ---------------- final loss reduction ----------------
__global__ void loss_kernel(const float* __restrict__ rowsum,
                            const float* __restrict__ crossdot, float* __restrict__ out) {
    __shared__ float red[256];
    float acc = 0.f;
    for (int i = threadIdx.x; i < 3 * 2 * N_ROWS; i += 256) {
        // diagonal never accumulated -> denom is rowsum directly
        acc += logf(rowsum[i]) - 2.f * crossdot[i];
    }
    red[threadIdx.x] = acc;
    __syncthreads();
    for (int s = 128; s > 0; s >>= 1) {
        if (threadIdx.x < s) red[threadIdx.x] += red[threadIdx.x + s];
        __syncthreads();
    }
    if (threadIdx.x == 0) out[0] = red[0] * (1.f / 24576.f);
}

// ---------------- launch ----------------
extern "C" void kernel_launch(void* const* d_in, const int* in_sizes, int n_in,
                              void* d_out, int out_size, void* d_ws, size_t ws_size,
                              hipStream_t stream) {
    const float* doc0   = (const float*)d_in[0];
    const float* doc1   = (const float*)d_in[1];
    const float* doc2   = (const float*)d_in[2];
    const float* W1s    = (const float*)d_in[3];
    const float* b1s    = (const float*)d_in[4];
    const float* gammas = (const float*)d_in[5];
    const float* betas  = (const float*)d_in[6];
    const float* W2s    = (const float*)d_in[7];
    const float* b2s    = (const float*)d_in[8];
    float* out = (float*)d_out;

    char* base = (char*)d_ws;
    size_t off = 0;
    auto alloc = [&](size_t bytes) -> char* {
        char* r = base + off;
        off += (bytes + 255) & ~(size_t)255;
        return r;
    };

    // Xb dead after gemm1 -> Abuf aliases it. H fp32 dead after bn_apply -> O bf16 aliases it.
    unsigned short* Xb   = (unsigned short*)alloc((size_t)3 * N_ROWS * IN_DIM * 2);
    unsigned short* W1t  = (unsigned short*)alloc((size_t)6 * OUT_DIM * IN_DIM * 2);
    unsigned short* W2t  = (unsigned short*)alloc((size_t)6 * OUT_DIM * OUT_DIM * 2);
    float*          H    = (float*)         alloc((size_t)6 * N_ROWS * OUT_DIM * 4);
    unsigned short* Hb   = (unsigned short*)alloc((size_t)6 * N_ROWS * OUT_DIM * 2);
    unsigned char*  Abuf = (unsigned char*)Xb;
    unsigned short* O    = (unsigned short*)H;
    char* zbase = alloc(24576 + 98304 + 98304);
    float* stats    = (float*)zbase;
    float* rowsumsq = (float*)(zbase + 24576);
    float* rowsum   = (float*)(zbase + 24576 + 98304);
    float* cdot     = (float*)alloc((size_t)3 * 2 * N_ROWS * 4);

    if (ws_size < off) return;

    prep<<<dim3(3072, 6), 256, 0, stream>>>(doc0, doc1, doc2, W1s, W2s, Xb, W1t, W2t, zbase);

    gemm1_bn<<<dim3(OUT_DIM / BN, N_ROWS / BM, 6), 256, 0, stream>>>(Xb, W1t, b1s, H, stats);

    bn_apply<<<(int)(((size_t)6 * N_ROWS * OUT_DIM / 4 + 255) / 256), 256, 0, stream>>>(
        H, Hb, stats, gammas, betas);

    gemm2_norm<<<dim3(OUT_DIM / BN, N_ROWS / BM, 6), 256, 0, stream>>>(Hb, W2t, b2s, O, rowsumsq);

    // fragment-major fp8 conversion: 1536 row-tiles of 16
    l2norm_fp8<<<1536, 256, 0, stream>>>(O, rowsumsq, Abuf);

    // barrier-free symmetric gram: 64*65/2 = 2080 tile-pairs per pair, 3 pairs
    gram_kernel<<<dim3(2080, 1, 3), 256, 0, stream>>>(Abuf, rowsum, cdot);

    loss_kernel<<<1, 256, 0, stream>>>(rowsum, cdot, out);
}

// Round 9
// 355.758 us; speedup vs baseline: 1.2702x; 1.0622x over previous
//
#include <hip/hip_runtime.h>
#include <hip/hip_bf16.h>
#include <hip/hip_fp8.h>

#define N_ROWS 4096
#define IN_DIM 768
#define OUT_DIM 512

// EVERYTHING fragment-major, ALL GEMMs barrier-free (no LDS anywhere).
// Fragment-major layout for an MFMA operand matrix (R rows, K cols):
//   unit = gt*(K/32) + kf   (gt = row>>4, kf = k>>5)
//   byte addr = (unit*64 + lane)*S,  S = 16 B (bf16: 8 elems; fp8: 16 elems=2 frags)
//   lane's elems: row = gt*16 + (lane&15), k = kf*32 + (lane>>4)*8 + j.
// Validated by R8 gram (absmax 0.0) for both A and B operands.

using bf16x8 = __attribute__((ext_vector_type(8))) short;
using f32x4  = __attribute__((ext_vector_type(4))) float;
using i64    = long;
using i64x2  = __attribute__((ext_vector_type(2))) long;

__device__ __constant__ int c_docmap[6] = {0, 1, 0, 2, 1, 2};

__device__ inline unsigned short f2bf(float f) {
    __hip_bfloat16 h = __float2bfloat16(f);
    return reinterpret_cast<unsigned short&>(h);
}
__device__ inline float bf2f(unsigned short u) {
    return __uint_as_float((unsigned int)u << 16);
}
__device__ inline unsigned char f2fp8(float f) {
    __hip_fp8_e4m3 t(f);           // OCP e4m3fn, RNE+sat
    return t.__x;
}
__device__ inline uint4 pack8bf(const float* v) {
    uint4 o;
    unsigned short* p = (unsigned short*)&o;
#pragma unroll
    for (int j = 0; j < 8; ++j) p[j] = f2bf(v[j]);
    return o;
}

// ---------------- prep: all conversions to fragment-major + zero-init ----------------
// wave-units: [0,18432) docs (3 x 256gt x 24kf); [18432,23040) W1 (6 x 32 x 24);
// [23040,26112) W2 (6 x 32 x 16); rest zero-init (216 units).
__global__ __launch_bounds__(256) void prep(
    const float* __restrict__ d0, const float* __restrict__ d1,
    const float* __restrict__ d2, const float* __restrict__ W1s,
    const float* __restrict__ W2s, unsigned short* __restrict__ Xb,
    unsigned short* __restrict__ W1t, unsigned short* __restrict__ W2t,
    char* __restrict__ zbase) {
    int wunit = blockIdx.x * 4 + (threadIdx.x >> 6);
    int lane = threadIdx.x & 63;
    int lane15 = lane & 15, quad = lane >> 4;
    if (wunit < 18432) {
        int d = wunit / 6144, u = wunit % 6144;       // 256 gt x 24 kf
        int gt = u / 24, kf = u % 24;
        const float* src = (d == 0) ? d0 : ((d == 1) ? d1 : d2);
        const float* s = src + (size_t)(gt * 16 + lane15) * IN_DIM + kf * 32 + quad * 8;
        float4 a = *(const float4*)s, b = *(const float4*)(s + 4);
        float v[8] = {a.x, a.y, a.z, a.w, b.x, b.y, b.z, b.w};
        *(uint4*)(Xb + (size_t)d * N_ROWS * IN_DIM + (size_t)u * 512 + lane * 8) = pack8bf(v);
    } else if (wunit < 23040) {
        int v0 = wunit - 18432;
        int z = v0 / 768, u = v0 % 768;               // 32 gt x 24 kf
        int gt = u / 24, kf = u % 24;
        int n = gt * 16 + lane15;
        int k0 = kf * 32 + quad * 8;
        const float* W = W1s + (size_t)z * IN_DIM * OUT_DIM;
        float v[8];
#pragma unroll
        for (int j = 0; j < 8; ++j) v[j] = W[(size_t)(k0 + j) * OUT_DIM + n];
        *(uint4*)(W1t + (size_t)z * OUT_DIM * IN_DIM + (size_t)u * 512 + lane * 8) = pack8bf(v);
    } else if (wunit < 26112) {
        int v0 = wunit - 23040;
        int z = v0 / 512, u = v0 % 512;               // 32 gt x 16 kf
        int gt = u / 16, kf = u % 16;
        int n = gt * 16 + lane15;
        int k0 = kf * 32 + quad * 8;
        const float* W = W2s + (size_t)z * OUT_DIM * OUT_DIM;
        float v[8];
#pragma unroll
        for (int j = 0; j < 8; ++j) v[j] = W[(size_t)(k0 + j) * OUT_DIM + n];
        *(uint4*)(W2t + (size_t)z * OUT_DIM * OUT_DIM + (size_t)u * 512 + lane * 8) = pack8bf(v);
    } else {
        size_t b = (size_t)(wunit - 26112) * 1024 + (size_t)lane * 16;
        if (b < (size_t)(24576 + 98304 + 98304))
            *(float4*)(zbase + b) = (float4){0.f, 0.f, 0.f, 0.f};
    }
}

// ---------------- GEMM1: barrier-free, fused BN-stats, FP32 out ----------------
__global__ __launch_bounds__(256) void gemm1_bn(
    const unsigned short* __restrict__ Xb, const unsigned short* __restrict__ W1t,
    const float* __restrict__ biasAll, float* __restrict__ H,
    float* __restrict__ stats) {
    const int NKF = IN_DIM / 32;   // 24
    int z = blockIdx.z;
    const unsigned short* A = Xb + (size_t)c_docmap[z] * N_ROWS * IN_DIM;
    const unsigned short* B = W1t + (size_t)z * OUT_DIM * IN_DIM;
    const float* bz = biasAll + (size_t)z * OUT_DIM;
    float* C = H + (size_t)z * N_ROWS * OUT_DIM;

    int m0 = blockIdx.y * 128, n0 = blockIdx.x * 128;
    int tid = threadIdx.x;
    int wave = tid >> 6, lane = tid & 63;
    int lane15 = lane & 15, quad = lane >> 4;
    int wrow = (wave >> 1) * 64, wcol = (wave & 1) * 64;

    const unsigned short* Ca = A + (size_t)((m0 + wrow) >> 4) * NKF * 512 + (size_t)lane * 8;
    const unsigned short* Cb = B + (size_t)((n0 + wcol) >> 4) * NKF * 512 + (size_t)lane * 8;

    f32x4 acc[4][4];
#pragma unroll
    for (int mt = 0; mt < 4; ++mt)
#pragma unroll
        for (int nt = 0; nt < 4; ++nt)
            acc[mt][nt] = (f32x4){0.f, 0.f, 0.f, 0.f};

    bf16x8 aC[4], bC[4], aN[4], bN[4];
#pragma unroll
    for (int t = 0; t < 4; ++t) {
        aC[t] = *(const bf16x8*)(Ca + (size_t)t * NKF * 512);
        bC[t] = *(const bf16x8*)(Cb + (size_t)t * NKF * 512);
    }
#pragma unroll
    for (int kf = 0; kf < NKF; ++kf) {
        if (kf < NKF - 1) {
#pragma unroll
            for (int t = 0; t < 4; ++t) {
                aN[t] = *(const bf16x8*)(Ca + (size_t)t * NKF * 512 + (kf + 1) * 512);
                bN[t] = *(const bf16x8*)(Cb + (size_t)t * NKF * 512 + (kf + 1) * 512);
            }
        }
#pragma unroll
        for (int mt = 0; mt < 4; ++mt)
#pragma unroll
            for (int nt = 0; nt < 4; ++nt)
                acc[mt][nt] = __builtin_amdgcn_mfma_f32_16x16x32_bf16(aC[mt], bC[nt], acc[mt][nt], 0, 0, 0);
#pragma unroll
        for (int t = 0; t < 4; ++t) { aC[t] = aN[t]; bC[t] = bN[t]; }
    }

    float s1[4] = {0.f, 0.f, 0.f, 0.f}, s2[4] = {0.f, 0.f, 0.f, 0.f};
#pragma unroll
    for (int nt = 0; nt < 4; ++nt) {
        int col = n0 + wcol + nt * 16 + lane15;
        float bv = bz[col];
#pragma unroll
        for (int mt = 0; mt < 4; ++mt)
#pragma unroll
            for (int r = 0; r < 4; ++r) {
                int row = m0 + wrow + mt * 16 + quad * 4 + r;
                float v = acc[mt][nt][r] + bv;
                C[(size_t)row * OUT_DIM + col] = v;
                s1[nt] += v; s2[nt] += v * v;
            }
    }
#pragma unroll
    for (int nt = 0; nt < 4; ++nt) {
        float a = s1[nt], b = s2[nt];
        a += __shfl_xor(a, 16); a += __shfl_xor(a, 32);
        b += __shfl_xor(b, 16); b += __shfl_xor(b, 32);
        if (quad == 0) {
            int col = n0 + wcol + nt * 16 + lane15;
            atomicAdd(&stats[((size_t)z * OUT_DIM + col) * 2 + 0], a);
            atomicAdd(&stats[((size_t)z * OUT_DIM + col) * 2 + 1], b);
        }
    }
}

// ---------------- BN apply + ReLU: fp32 H -> bf16 Hb (FRAGMENT-MAJOR) ----------------
// wave-units: 6 z x 256 gt x 16 kf = 24576.
__global__ __launch_bounds__(256) void bn_apply(
    const float* __restrict__ H, unsigned short* __restrict__ Hb,
    const float* __restrict__ stats, const float* __restrict__ gammas,
    const float* __restrict__ betas) {
    int wunit = blockIdx.x * 4 + (threadIdx.x >> 6);
    if (wunit >= 24576) return;
    int lane = threadIdx.x & 63;
    int lane15 = lane & 15, quad = lane >> 4;
    int z = wunit / 4096, u = wunit % 4096;       // 256 gt x 16 kf
    int gt = u / 16, kf = u % 16;
    int row = gt * 16 + lane15;
    int k = kf * 32 + quad * 8;
    const float* Hp = H + ((size_t)z * N_ROWS + row) * OUT_DIM + k;
    float4 a = *(const float4*)Hp, b = *(const float4*)(Hp + 4);
    float hv[8] = {a.x, a.y, a.z, a.w, b.x, b.y, b.z, b.w};
    float v[8];
#pragma unroll
    for (int j = 0; j < 8; ++j) {
        size_t sc = (size_t)z * OUT_DIM + k + j;
        float mu = stats[sc * 2 + 0] * (1.f / N_ROWS);
        float var = stats[sc * 2 + 1] * (1.f / N_ROWS) - mu * mu;
        float t = (hv[j] - mu) * rsqrtf(var + 1e-5f) * gammas[sc] + betas[sc];
        v[j] = fmaxf(t, 0.f);
    }
    *(uint4*)(Hb + (size_t)z * N_ROWS * OUT_DIM + (size_t)u * 512 + lane * 8) = pack8bf(v);
}

// ---------------- GEMM2: barrier-free, fused row-sumsq, BF16 row-major out ----------------
__global__ __launch_bounds__(256) void gemm2_norm(
    const unsigned short* __restrict__ Hb, const unsigned short* __restrict__ W2t,
    const float* __restrict__ biasAll, unsigned short* __restrict__ O,
    float* __restrict__ rowsumsq) {
    const int NKF = OUT_DIM / 32;  // 16
    int z = blockIdx.z;
    const unsigned short* A = Hb + (size_t)z * N_ROWS * OUT_DIM;
    const unsigned short* B = W2t + (size_t)z * OUT_DIM * OUT_DIM;
    const float* bz = biasAll + (size_t)z * OUT_DIM;
    unsigned short* C = O + (size_t)z * N_ROWS * OUT_DIM;
    float* rq = rowsumsq + (size_t)z * N_ROWS;

    int m0 = blockIdx.y * 128, n0 = blockIdx.x * 128;
    int tid = threadIdx.x;
    int wave = tid >> 6, lane = tid & 63;
    int lane15 = lane & 15, quad = lane >> 4;
    int wrow = (wave >> 1) * 64, wcol = (wave & 1) * 64;

    const unsigned short* Ca = A + (size_t)((m0 + wrow) >> 4) * NKF * 512 + (size_t)lane * 8;
    const unsigned short* Cb = B + (size_t)((n0 + wcol) >> 4) * NKF * 512 + (size_t)lane * 8;

    f32x4 acc[4][4];
#pragma unroll
    for (int mt = 0; mt < 4; ++mt)
#pragma unroll
        for (int nt = 0; nt < 4; ++nt)
            acc[mt][nt] = (f32x4){0.f, 0.f, 0.f, 0.f};

    bf16x8 aC[4], bC[4], aN[4], bN[4];
#pragma unroll
    for (int t = 0; t < 4; ++t) {
        aC[t] = *(const bf16x8*)(Ca + (size_t)t * NKF * 512);
        bC[t] = *(const bf16x8*)(Cb + (size_t)t * NKF * 512);
    }
#pragma unroll
    for (int kf = 0; kf < NKF; ++kf) {
        if (kf < NKF - 1) {
#pragma unroll
            for (int t = 0; t < 4; ++t) {
                aN[t] = *(const bf16x8*)(Ca + (size_t)t * NKF * 512 + (kf + 1) * 512);
                bN[t] = *(const bf16x8*)(Cb + (size_t)t * NKF * 512 + (kf + 1) * 512);
            }
        }
#pragma unroll
        for (int mt = 0; mt < 4; ++mt)
#pragma unroll
            for (int nt = 0; nt < 4; ++nt)
                acc[mt][nt] = __builtin_amdgcn_mfma_f32_16x16x32_bf16(aC[mt], bC[nt], acc[mt][nt], 0, 0, 0);
#pragma unroll
        for (int t = 0; t < 4; ++t) { aC[t] = aN[t]; bC[t] = bN[t]; }
    }

    float rs[16];
#pragma unroll
    for (int j = 0; j < 16; ++j) rs[j] = 0.f;
#pragma unroll
    for (int nt = 0; nt < 4; ++nt) {
        int col = n0 + wcol + nt * 16 + lane15;
        float bv = bz[col];
#pragma unroll
        for (int mt = 0; mt < 4; ++mt)
#pragma unroll
            for (int r = 0; r < 4; ++r) {
                int row = m0 + wrow + mt * 16 + quad * 4 + r;
                float v = acc[mt][nt][r] + bv;
                C[(size_t)row * OUT_DIM + col] = f2bf(v);
                rs[mt * 4 + r] += v * v;
            }
    }
#pragma unroll
    for (int j = 0; j < 16; ++j) {
        float v = rs[j];
        v += __shfl_xor(v, 1); v += __shfl_xor(v, 2);
        v += __shfl_xor(v, 4); v += __shfl_xor(v, 8);
        if (lane15 == 0) {
            int row = m0 + wrow + (j >> 2) * 16 + quad * 4 + (j & 3);
            atomicAdd(&rq[row], v);
        }
    }
}

// ---------------- row L2 norm: bf16 O -> fp8 e4m3, fragment-major ----------------
__global__ __launch_bounds__(256) void l2norm_fp8(const unsigned short* __restrict__ O,
                                                  const float* __restrict__ rowsumsq,
                                                  unsigned char* __restrict__ A) {
    int gt = blockIdx.x;                  // 0..1535
    int wave = threadIdx.x >> 6, lane = threadIdx.x & 63;
    int lane15 = lane & 15, quad = lane >> 4;
    int row = gt * 16 + lane15;
    float sc = 1.f / fmaxf(sqrtf(rowsumsq[row]), 1e-12f);
    const unsigned short* Op = O + (size_t)row * OUT_DIM + quad * 8;
#pragma unroll
    for (int t = 0; t < 2; ++t) {
        int kh = wave * 2 + t;
        unsigned long long pk[2];
#pragma unroll
        for (int half = 0; half < 2; ++half) {
            int kf = kh * 2 + half;
            uint4 u = *(const uint4*)(Op + kf * 32);
            unsigned int w[4] = {u.x, u.y, u.z, u.w};
            unsigned long long v = 0;
#pragma unroll
            for (int j = 0; j < 8; ++j) {
                unsigned short us = (j & 1) ? (unsigned short)(w[j >> 1] >> 16)
                                            : (unsigned short)(w[j >> 1] & 0xffff);
                v |= (unsigned long long)f2fp8(bf2f(us) * sc) << (8 * j);
            }
            pk[half] = v;
        }
        i64x2 st; st[0] = (i64)pk[0]; st[1] = (i64)pk[1];
        *(i64x2*)(A + ((size_t)(gt * 8 + kh) * 64 + lane) * 16) = st;
    }
}

// ---------------- barrier-free fp8 Gram, specialized epilogues ----------------
__global__ __launch_bounds__(256) void gram_kernel(const unsigned char* __restrict__ Abase,
                                                   float* __restrict__ rowsum,
                                                   float* __restrict__ crossdot) {
    int p = blockIdx.z;
    const unsigned char* Cm = Abase + (size_t)p * 2 * N_ROWS * OUT_DIM;

    int idx = blockIdx.x, I = 0;
    while (idx >= 64 - I) { idx -= 64 - I; ++I; }
    int J = I + idx;
    int m0 = I * 128, n0 = J * 128;

    int tid = threadIdx.x;
    int wave = tid >> 6, lane = tid & 63;
    int lane15 = lane & 15, quad = lane >> 4;
    int wrow = (wave >> 1) * 64, wcol = (wave & 1) * 64;

    const unsigned char* Ca = Cm + (size_t)((m0 + wrow) >> 4) * 8192 + (size_t)lane * 16;
    const unsigned char* Cb = Cm + (size_t)((n0 + wcol) >> 4) * 8192 + (size_t)lane * 16;

    f32x4 acc[4][4];
#pragma unroll
    for (int mt = 0; mt < 4; ++mt)
#pragma unroll
        for (int nt = 0; nt < 4; ++nt)
            acc[mt][nt] = (f32x4){0.f, 0.f, 0.f, 0.f};

    i64x2 aC[4], bC[4], aN[4], bN[4];
#pragma unroll
    for (int t = 0; t < 4; ++t) {
        aC[t] = *(const i64x2*)(Ca + (size_t)t * 8192);
        bC[t] = *(const i64x2*)(Cb + (size_t)t * 8192);
    }
#pragma unroll
    for (int kh = 0; kh < 8; ++kh) {
        if (kh < 7) {
#pragma unroll
            for (int t = 0; t < 4; ++t) {
                aN[t] = *(const i64x2*)(Ca + (size_t)t * 8192 + (kh + 1) * 1024);
                bN[t] = *(const i64x2*)(Cb + (size_t)t * 8192 + (kh + 1) * 1024);
            }
        }
#pragma unroll
        for (int half = 0; half < 2; ++half)
#pragma unroll
            for (int mt = 0; mt < 4; ++mt)
#pragma unroll
                for (int nt = 0; nt < 4; ++nt)
                    acc[mt][nt] = __builtin_amdgcn_mfma_f32_16x16x32_fp8_fp8(
                        aC[mt][half], bC[nt][half], acc[mt][nt], 0, 0, 0);
#pragma unroll
        for (int t = 0; t < 4; ++t) { aC[t] = aN[t]; bC[t] = bN[t]; }
    }

    float* cdp = crossdot + (size_t)p * 2 * N_ROWS;
    float* rp  = rowsum  + (size_t)p * 2 * N_ROWS;

    float rs[16];
    float cs[4] = {0.f, 0.f, 0.f, 0.f};
#pragma unroll
    for (int j = 0; j < 16; ++j) rs[j] = 0.f;

    if (I < J) {
        bool isCross = (J == I + N_ROWS / 128);
#pragma unroll
        for (int mt = 0; mt < 4; ++mt)
#pragma unroll
            for (int nt = 0; nt < 4; ++nt)
#pragma unroll
                for (int r = 0; r < 4; ++r) {
                    float e = __expf(2.f * acc[mt][nt][r]);
                    rs[mt * 4 + r] += e;
                    cs[nt] += e;
                }
        if (isCross) {
            // cross diagonal: gcol == grow + 4096 <=> local col == local row
#pragma unroll
            for (int mt = 0; mt < 4; ++mt)
#pragma unroll
                for (int nt = 0; nt < 4; ++nt) {
                    int lcol = wcol + nt * 16 + lane15;
#pragma unroll
                    for (int r = 0; r < 4; ++r) {
                        int lrow = wrow + mt * 16 + quad * 4 + r;
                        if (lcol == lrow) {
                            float s = acc[mt][nt][r];
                            cdp[m0 + lrow] = s;
                            cdp[n0 + lcol] = s;
                        }
                    }
                }
        }
    } else {
        // diagonal block: strict upper triangle only
#pragma unroll
        for (int mt = 0; mt < 4; ++mt)
#pragma unroll
            for (int nt = 0; nt < 4; ++nt) {
                int gcol = n0 + wcol + nt * 16 + lane15;
#pragma unroll
                for (int r = 0; r < 4; ++r) {
                    int grow = m0 + wrow + mt * 16 + quad * 4 + r;
                    if (grow < gcol) {
                        float e = __expf(2.f * acc[mt][nt][r]);
                        rs[mt * 4 + r] += e;
                        cs[nt] += e;
                    }
                }
            }
    }

#pragma unroll
    for (int j = 0; j < 16; ++j) {
        float v = rs[j];
        v += __shfl_xor(v, 1); v += __shfl_xor(v, 2);
        v += __shfl_xor(v, 4); v += __shfl_xor(v, 8);
        rs[j] = v;
    }
    if (lane15 == 0) {
#pragma unroll
        for (int j = 0; j < 16; ++j) {
            int grow = m0 + wrow + (j >> 2) * 16 + quad * 4 + (j & 3);
            atomicAdd(&rp[grow], rs[j]);
        }
    }
#pragma unroll
    for (int n = 0; n < 4; ++n) {
        float v = cs[n];
        v += __shfl_xor(v, 16); v += __shfl_xor(v, 32);
        cs[n] = v;
    }
    if (quad == 0) {
#pragma unroll
        for (int n = 0; n < 4; ++n) {
            int gcol = n0 + wcol + n * 16 + lane15;
            atomicAdd(&rp[gcol], cs[n]);
        }
    }
}

// ---------------- final loss reduction ----------------
__global__ void loss_kernel(const float* __restrict__ rowsum,
                            const float* __restrict__ crossdot, float* __restrict__ out) {
    __shared__ float red[256];
    float acc = 0.f;
    for (int i = threadIdx.x; i < 3 * 2 * N_ROWS; i += 256) {
        acc += logf(rowsum[i]) - 2.f * crossdot[i];
    }
    red[threadIdx.x] = acc;
    __syncthreads();
    for (int s = 128; s > 0; s >>= 1) {
        if (threadIdx.x < s) red[threadIdx.x] += red[threadIdx.x + s];
        __syncthreads();
    }
    if (threadIdx.x == 0) out[0] = red[0] * (1.f / 24576.f);
}

// ---------------- launch ----------------
extern "C" void kernel_launch(void* const* d_in, const int* in_sizes, int n_in,
                              void* d_out, int out_size, void* d_ws, size_t ws_size,
                              hipStream_t stream) {
    const float* doc0   = (const float*)d_in[0];
    const float* doc1   = (const float*)d_in[1];
    const float* doc2   = (const float*)d_in[2];
    const float* W1s    = (const float*)d_in[3];
    const float* b1s    = (const float*)d_in[4];
    const float* gammas = (const float*)d_in[5];
    const float* betas  = (const float*)d_in[6];
    const float* W2s    = (const float*)d_in[7];
    const float* b2s    = (const float*)d_in[8];
    float* out = (float*)d_out;

    char* base = (char*)d_ws;
    size_t off = 0;
    auto alloc = [&](size_t bytes) -> char* {
        char* r = base + off;
        off += (bytes + 255) & ~(size_t)255;
        return r;
    };

    unsigned short* Xb   = (unsigned short*)alloc((size_t)3 * N_ROWS * IN_DIM * 2);
    unsigned short* W1t  = (unsigned short*)alloc((size_t)6 * OUT_DIM * IN_DIM * 2);
    unsigned short* W2t  = (unsigned short*)alloc((size_t)6 * OUT_DIM * OUT_DIM * 2);
    float*          H    = (float*)         alloc((size_t)6 * N_ROWS * OUT_DIM * 4);
    unsigned short* Hb   = (unsigned short*)alloc((size_t)6 * N_ROWS * OUT_DIM * 2);
    unsigned char*  Abuf = (unsigned char*)Xb;    // Xb dead after gemm1
    unsigned short* O    = (unsigned short*)H;    // H dead after bn_apply
    char* zbase = alloc(24576 + 98304 + 98304);
    float* stats    = (float*)zbase;
    float* rowsumsq = (float*)(zbase + 24576);
    float* rowsum   = (float*)(zbase + 24576 + 98304);
    float* cdot     = (float*)alloc((size_t)3 * 2 * N_ROWS * 4);

    if (ws_size < off) return;

    // 26112 conversion wave-units + 216 zero units -> 6582 blocks
    prep<<<6582, 256, 0, stream>>>(doc0, doc1, doc2, W1s, W2s, Xb, W1t, W2t, zbase);

    gemm1_bn<<<dim3(OUT_DIM / 128, N_ROWS / 128, 6), 256, 0, stream>>>(Xb, W1t, b1s, H, stats);

    bn_apply<<<6144, 256, 0, stream>>>(H, Hb, stats, gammas, betas);

    gemm2_norm<<<dim3(OUT_DIM / 128, N_ROWS / 128, 6), 256, 0, stream>>>(Hb, W2t, b2s, O, rowsumsq);

    l2norm_fp8<<<1536, 256, 0, stream>>>(O, rowsumsq, Abuf);

    // barrier-free symmetric gram: 2080 tile-pairs per pair, 3 pairs
    gram_kernel<<<dim3(2080, 1, 3), 256, 0, stream>>>(Abuf, rowsum, cdot);

    loss_kernel<<<1, 256, 0, stream>>>(rowsum, cdot, out);
}

// Round 10
// 339.275 us; speedup vs baseline: 1.3319x; 1.0486x over previous
//
#include <hip/hip_runtime.h>
#include <hip/hip_bf16.h>
#include <hip/hip_fp8.h>

#define N_ROWS 4096
#define IN_DIM 768
#define OUT_DIM 512

// All operands fragment-major, all GEMMs barrier-free (no LDS).
// Fragment-major (R rows, K cols): unit = gt*(K/32)+kf (gt=row>>4, kf=k>>5),
// byte addr = (unit*64+lane)*16; lane elems: row = gt*16+(lane&15),
// k = kf*32+(lane>>4)*8+j. bf16: 8 elems/lane/frag; fp8: 16 = 2 frags.
// R10: 256x128 supertiles (512 thr, 8 waves x 64x64), masked J>=2I gram
// enumeration + XCD-contiguous swizzle for L2 locality.

using bf16x8 = __attribute__((ext_vector_type(8))) short;
using f32x4  = __attribute__((ext_vector_type(4))) float;
using i64    = long;
using i64x2  = __attribute__((ext_vector_type(2))) long;

__device__ __constant__ int c_docmap[6] = {0, 1, 0, 2, 1, 2};

__device__ inline unsigned short f2bf(float f) {
    __hip_bfloat16 h = __float2bfloat16(f);
    return reinterpret_cast<unsigned short&>(h);
}
__device__ inline float bf2f(unsigned short u) {
    return __uint_as_float((unsigned int)u << 16);
}
__device__ inline unsigned char f2fp8(float f) {
    __hip_fp8_e4m3 t(f);           // OCP e4m3fn, RNE+sat
    return t.__x;
}
__device__ inline uint4 pack8bf(const float* v) {
    uint4 o;
    unsigned short* p = (unsigned short*)&o;
#pragma unroll
    for (int j = 0; j < 8; ++j) p[j] = f2bf(v[j]);
    return o;
}

// ---------------- prep: conversions to fragment-major + zero-init ----------------
__global__ __launch_bounds__(256) void prep(
    const float* __restrict__ d0, const float* __restrict__ d1,
    const float* __restrict__ d2, const float* __restrict__ W1s,
    const float* __restrict__ W2s, unsigned short* __restrict__ Xb,
    unsigned short* __restrict__ W1t, unsigned short* __restrict__ W2t,
    char* __restrict__ zbase) {
    int wunit = blockIdx.x * 4 + (threadIdx.x >> 6);
    int lane = threadIdx.x & 63;
    int lane15 = lane & 15, quad = lane >> 4;
    if (wunit < 18432) {
        int d = wunit / 6144, u = wunit % 6144;       // 256 gt x 24 kf
        int gt = u / 24, kf = u % 24;
        const float* src = (d == 0) ? d0 : ((d == 1) ? d1 : d2);
        const float* s = src + (size_t)(gt * 16 + lane15) * IN_DIM + kf * 32 + quad * 8;
        float4 a = *(const float4*)s, b = *(const float4*)(s + 4);
        float v[8] = {a.x, a.y, a.z, a.w, b.x, b.y, b.z, b.w};
        *(uint4*)(Xb + (size_t)d * N_ROWS * IN_DIM + (size_t)u * 512 + lane * 8) = pack8bf(v);
    } else if (wunit < 23040) {
        int v0 = wunit - 18432;
        int z = v0 / 768, u = v0 % 768;               // 32 gt x 24 kf
        int gt = u / 24, kf = u % 24;
        int n = gt * 16 + lane15;
        int k0 = kf * 32 + quad * 8;
        const float* W = W1s + (size_t)z * IN_DIM * OUT_DIM;
        float v[8];
#pragma unroll
        for (int j = 0; j < 8; ++j) v[j] = W[(size_t)(k0 + j) * OUT_DIM + n];
        *(uint4*)(W1t + (size_t)z * OUT_DIM * IN_DIM + (size_t)u * 512 + lane * 8) = pack8bf(v);
    } else if (wunit < 26112) {
        int v0 = wunit - 23040;
        int z = v0 / 512, u = v0 % 512;               // 32 gt x 16 kf
        int gt = u / 16, kf = u % 16;
        int n = gt * 16 + lane15;
        int k0 = kf * 32 + quad * 8;
        const float* W = W2s + (size_t)z * OUT_DIM * OUT_DIM;
        float v[8];
#pragma unroll
        for (int j = 0; j < 8; ++j) v[j] = W[(size_t)(k0 + j) * OUT_DIM + n];
        *(uint4*)(W2t + (size_t)z * OUT_DIM * OUT_DIM + (size_t)u * 512 + lane * 8) = pack8bf(v);
    } else {
        size_t b = (size_t)(wunit - 26112) * 1024 + (size_t)lane * 16;
        if (b < (size_t)(24576 + 98304 + 98304))
            *(float4*)(zbase + b) = (float4){0.f, 0.f, 0.f, 0.f};
    }
}

// ---------------- GEMM1: 256x128 supertile, barrier-free, fused BN-stats ----------------
__global__ __launch_bounds__(512) void gemm1_bn(
    const unsigned short* __restrict__ Xb, const unsigned short* __restrict__ W1t,
    const float* __restrict__ biasAll, float* __restrict__ H,
    float* __restrict__ stats) {
    const int NKF = IN_DIM / 32;   // 24
    int z = blockIdx.z;
    const unsigned short* A = Xb + (size_t)c_docmap[z] * N_ROWS * IN_DIM;
    const unsigned short* B = W1t + (size_t)z * OUT_DIM * IN_DIM;
    const float* bz = biasAll + (size_t)z * OUT_DIM;
    float* C = H + (size_t)z * N_ROWS * OUT_DIM;

    int m0 = blockIdx.y * 256, n0 = blockIdx.x * 128;
    int tid = threadIdx.x;
    int wave = tid >> 6, lane = tid & 63;
    int lane15 = lane & 15, quad = lane >> 4;
    int wrow = (wave >> 1) * 64, wcol = (wave & 1) * 64;

    const unsigned short* Ca = A + (size_t)((m0 + wrow) >> 4) * NKF * 512 + (size_t)lane * 8;
    const unsigned short* Cb = B + (size_t)((n0 + wcol) >> 4) * NKF * 512 + (size_t)lane * 8;

    f32x4 acc[4][4];
#pragma unroll
    for (int mt = 0; mt < 4; ++mt)
#pragma unroll
        for (int nt = 0; nt < 4; ++nt)
            acc[mt][nt] = (f32x4){0.f, 0.f, 0.f, 0.f};

    bf16x8 aC[4], bC[4], aN[4], bN[4];
#pragma unroll
    for (int t = 0; t < 4; ++t) {
        aC[t] = *(const bf16x8*)(Ca + (size_t)t * NKF * 512);
        bC[t] = *(const bf16x8*)(Cb + (size_t)t * NKF * 512);
    }
#pragma unroll
    for (int kf = 0; kf < NKF; ++kf) {
        if (kf < NKF - 1) {
#pragma unroll
            for (int t = 0; t < 4; ++t) {
                aN[t] = *(const bf16x8*)(Ca + (size_t)t * NKF * 512 + (kf + 1) * 512);
                bN[t] = *(const bf16x8*)(Cb + (size_t)t * NKF * 512 + (kf + 1) * 512);
            }
        }
#pragma unroll
        for (int mt = 0; mt < 4; ++mt)
#pragma unroll
            for (int nt = 0; nt < 4; ++nt)
                acc[mt][nt] = __builtin_amdgcn_mfma_f32_16x16x32_bf16(aC[mt], bC[nt], acc[mt][nt], 0, 0, 0);
#pragma unroll
        for (int t = 0; t < 4; ++t) { aC[t] = aN[t]; bC[t] = bN[t]; }
    }

    float s1[4] = {0.f, 0.f, 0.f, 0.f}, s2[4] = {0.f, 0.f, 0.f, 0.f};
#pragma unroll
    for (int nt = 0; nt < 4; ++nt) {
        int col = n0 + wcol + nt * 16 + lane15;
        float bv = bz[col];
#pragma unroll
        for (int mt = 0; mt < 4; ++mt)
#pragma unroll
            for (int r = 0; r < 4; ++r) {
                int row = m0 + wrow + mt * 16 + quad * 4 + r;
                float v = acc[mt][nt][r] + bv;
                C[(size_t)row * OUT_DIM + col] = v;
                s1[nt] += v; s2[nt] += v * v;
            }
    }
#pragma unroll
    for (int nt = 0; nt < 4; ++nt) {
        float a = s1[nt], b = s2[nt];
        a += __shfl_xor(a, 16); a += __shfl_xor(a, 32);
        b += __shfl_xor(b, 16); b += __shfl_xor(b, 32);
        if (quad == 0) {
            int col = n0 + wcol + nt * 16 + lane15;
            atomicAdd(&stats[((size_t)z * OUT_DIM + col) * 2 + 0], a);
            atomicAdd(&stats[((size_t)z * OUT_DIM + col) * 2 + 1], b);
        }
    }
}

// ---------------- BN apply + ReLU: fp32 H -> bf16 Hb (fragment-major) ----------------
__global__ __launch_bounds__(256) void bn_apply(
    const float* __restrict__ H, unsigned short* __restrict__ Hb,
    const float* __restrict__ stats, const float* __restrict__ gammas,
    const float* __restrict__ betas) {
    int wunit = blockIdx.x * 4 + (threadIdx.x >> 6);
    if (wunit >= 24576) return;
    int lane = threadIdx.x & 63;
    int lane15 = lane & 15, quad = lane >> 4;
    int z = wunit / 4096, u = wunit % 4096;       // 256 gt x 16 kf
    int gt = u / 16, kf = u % 16;
    int row = gt * 16 + lane15;
    int k = kf * 32 + quad * 8;
    const float* Hp = H + ((size_t)z * N_ROWS + row) * OUT_DIM + k;
    float4 a = *(const float4*)Hp, b = *(const float4*)(Hp + 4);
    float hv[8] = {a.x, a.y, a.z, a.w, b.x, b.y, b.z, b.w};
    float v[8];
#pragma unroll
    for (int j = 0; j < 8; ++j) {
        size_t sc = (size_t)z * OUT_DIM + k + j;
        float mu = stats[sc * 2 + 0] * (1.f / N_ROWS);
        float var = stats[sc * 2 + 1] * (1.f / N_ROWS) - mu * mu;
        float t = (hv[j] - mu) * rsqrtf(var + 1e-5f) * gammas[sc] + betas[sc];
        v[j] = fmaxf(t, 0.f);
    }
    *(uint4*)(Hb + (size_t)z * N_ROWS * OUT_DIM + (size_t)u * 512 + lane * 8) = pack8bf(v);
}

// ---------------- GEMM2: 256x128 supertile, barrier-free, fused row-sumsq ----------------
__global__ __launch_bounds__(512) void gemm2_norm(
    const unsigned short* __restrict__ Hb, const unsigned short* __restrict__ W2t,
    const float* __restrict__ biasAll, unsigned short* __restrict__ O,
    float* __restrict__ rowsumsq) {
    const int NKF = OUT_DIM / 32;  // 16
    int z = blockIdx.z;
    const unsigned short* A = Hb + (size_t)z * N_ROWS * OUT_DIM;
    const unsigned short* B = W2t + (size_t)z * OUT_DIM * OUT_DIM;
    const float* bz = biasAll + (size_t)z * OUT_DIM;
    unsigned short* C = O + (size_t)z * N_ROWS * OUT_DIM;
    float* rq = rowsumsq + (size_t)z * N_ROWS;

    int m0 = blockIdx.y * 256, n0 = blockIdx.x * 128;
    int tid = threadIdx.x;
    int wave = tid >> 6, lane = tid & 63;
    int lane15 = lane & 15, quad = lane >> 4;
    int wrow = (wave >> 1) * 64, wcol = (wave & 1) * 64;

    const unsigned short* Ca = A + (size_t)((m0 + wrow) >> 4) * NKF * 512 + (size_t)lane * 8;
    const unsigned short* Cb = B + (size_t)((n0 + wcol) >> 4) * NKF * 512 + (size_t)lane * 8;

    f32x4 acc[4][4];
#pragma unroll
    for (int mt = 0; mt < 4; ++mt)
#pragma unroll
        for (int nt = 0; nt < 4; ++nt)
            acc[mt][nt] = (f32x4){0.f, 0.f, 0.f, 0.f};

    bf16x8 aC[4], bC[4], aN[4], bN[4];
#pragma unroll
    for (int t = 0; t < 4; ++t) {
        aC[t] = *(const bf16x8*)(Ca + (size_t)t * NKF * 512);
        bC[t] = *(const bf16x8*)(Cb + (size_t)t * NKF * 512);
    }
#pragma unroll
    for (int kf = 0; kf < NKF; ++kf) {
        if (kf < NKF - 1) {
#pragma unroll
            for (int t = 0; t < 4; ++t) {
                aN[t] = *(const bf16x8*)(Ca + (size_t)t * NKF * 512 + (kf + 1) * 512);
                bN[t] = *(const bf16x8*)(Cb + (size_t)t * NKF * 512 + (kf + 1) * 512);
            }
        }
#pragma unroll
        for (int mt = 0; mt < 4; ++mt)
#pragma unroll
            for (int nt = 0; nt < 4; ++nt)
                acc[mt][nt] = __builtin_amdgcn_mfma_f32_16x16x32_bf16(aC[mt], bC[nt], acc[mt][nt], 0, 0, 0);
#pragma unroll
        for (int t = 0; t < 4; ++t) { aC[t] = aN[t]; bC[t] = bN[t]; }
    }

    float rs[16];
#pragma unroll
    for (int j = 0; j < 16; ++j) rs[j] = 0.f;
#pragma unroll
    for (int nt = 0; nt < 4; ++nt) {
        int col = n0 + wcol + nt * 16 + lane15;
        float bv = bz[col];
#pragma unroll
        for (int mt = 0; mt < 4; ++mt)
#pragma unroll
            for (int r = 0; r < 4; ++r) {
                int row = m0 + wrow + mt * 16 + quad * 4 + r;
                float v = acc[mt][nt][r] + bv;
                C[(size_t)row * OUT_DIM + col] = f2bf(v);
                rs[mt * 4 + r] += v * v;
            }
    }
#pragma unroll
    for (int j = 0; j < 16; ++j) {
        float v = rs[j];
        v += __shfl_xor(v, 1); v += __shfl_xor(v, 2);
        v += __shfl_xor(v, 4); v += __shfl_xor(v, 8);
        if (lane15 == 0) {
            int row = m0 + wrow + (j >> 2) * 16 + quad * 4 + (j & 3);
            atomicAdd(&rq[row], v);
        }
    }
}

// ---------------- row L2 norm: bf16 O -> fp8 e4m3, fragment-major ----------------
__global__ __launch_bounds__(256) void l2norm_fp8(const unsigned short* __restrict__ O,
                                                  const float* __restrict__ rowsumsq,
                                                  unsigned char* __restrict__ A) {
    int gt = blockIdx.x;                  // 0..1535
    int wave = threadIdx.x >> 6, lane = threadIdx.x & 63;
    int lane15 = lane & 15, quad = lane >> 4;
    int row = gt * 16 + lane15;
    float sc = 1.f / fmaxf(sqrtf(rowsumsq[row]), 1e-12f);
    const unsigned short* Op = O + (size_t)row * OUT_DIM + quad * 8;
#pragma unroll
    for (int t = 0; t < 2; ++t) {
        int kh = wave * 2 + t;
        unsigned long long pk[2];
#pragma unroll
        for (int half = 0; half < 2; ++half) {
            int kf = kh * 2 + half;
            uint4 u = *(const uint4*)(Op + kf * 32);
            unsigned int w[4] = {u.x, u.y, u.z, u.w};
            unsigned long long v = 0;
#pragma unroll
            for (int j = 0; j < 8; ++j) {
                unsigned short us = (j & 1) ? (unsigned short)(w[j >> 1] >> 16)
                                            : (unsigned short)(w[j >> 1] & 0xffff);
                v |= (unsigned long long)f2fp8(bf2f(us) * sc) << (8 * j);
            }
            pk[half] = v;
        }
        i64x2 st; st[0] = (i64)pk[0]; st[1] = (i64)pk[1];
        *(i64x2*)(A + ((size_t)(gt * 8 + kh) * 64 + lane) * 16) = st;
    }
}

// ---------------- barrier-free fp8 Gram: 256x128 supertile, J>=2I masked ----------------
// 1D grid 3168 = 3 pairs x 1056 tile-pairs, XCD-contiguous swizzle.
__global__ __launch_bounds__(512) void gram_kernel(const unsigned char* __restrict__ Abase,
                                                   float* __restrict__ rowsum,
                                                   float* __restrict__ crossdot) {
    int px = blockIdx.x;
    int logical = (px & 7) * 396 + (px >> 3);     // 3168 = 8 * 396
    int p = logical / 1056;
    int t0 = logical - p * 1056;
    const unsigned char* Cm = Abase + (size_t)p * 2 * N_ROWS * OUT_DIM;

    int I = 0;
    while (t0 >= 64 - 2 * I) { t0 -= 64 - 2 * I; ++I; }
    int J = 2 * I + t0;
    int m0 = I * 256, n0 = J * 128;

    int tid = threadIdx.x;
    int wave = tid >> 6, lane = tid & 63;
    int lane15 = lane & 15, quad = lane >> 4;
    int wrow = (wave >> 1) * 64, wcol = (wave & 1) * 64;

    const unsigned char* Ca = Cm + (size_t)((m0 + wrow) >> 4) * 8192 + (size_t)lane * 16;
    const unsigned char* Cb = Cm + (size_t)((n0 + wcol) >> 4) * 8192 + (size_t)lane * 16;

    f32x4 acc[4][4];
#pragma unroll
    for (int mt = 0; mt < 4; ++mt)
#pragma unroll
        for (int nt = 0; nt < 4; ++nt)
            acc[mt][nt] = (f32x4){0.f, 0.f, 0.f, 0.f};

    i64x2 aC[4], bC[4], aN[4], bN[4];
#pragma unroll
    for (int t = 0; t < 4; ++t) {
        aC[t] = *(const i64x2*)(Ca + (size_t)t * 8192);
        bC[t] = *(const i64x2*)(Cb + (size_t)t * 8192);
    }
#pragma unroll
    for (int kh = 0; kh < 8; ++kh) {
        if (kh < 7) {
#pragma unroll
            for (int t = 0; t < 4; ++t) {
                aN[t] = *(const i64x2*)(Ca + (size_t)t * 8192 + (kh + 1) * 1024);
                bN[t] = *(const i64x2*)(Cb + (size_t)t * 8192 + (kh + 1) * 1024);
            }
        }
#pragma unroll
        for (int half = 0; half < 2; ++half)
#pragma unroll
            for (int mt = 0; mt < 4; ++mt)
#pragma unroll
                for (int nt = 0; nt < 4; ++nt)
                    acc[mt][nt] = __builtin_amdgcn_mfma_f32_16x16x32_fp8_fp8(
                        aC[mt][half], bC[nt][half], acc[mt][nt], 0, 0, 0);
#pragma unroll
        for (int t = 0; t < 4; ++t) { aC[t] = aN[t]; bC[t] = bN[t]; }
    }

    float* cdp = crossdot + (size_t)p * 2 * N_ROWS;
    float* rp  = rowsum  + (size_t)p * 2 * N_ROWS;

    float rs[16];
    float cs[4] = {0.f, 0.f, 0.f, 0.f};
#pragma unroll
    for (int j = 0; j < 16; ++j) rs[j] = 0.f;

    if (J >= 2 * I + 2) {
        // fully above diagonal: unmasked accumulation
#pragma unroll
        for (int mt = 0; mt < 4; ++mt)
#pragma unroll
            for (int nt = 0; nt < 4; ++nt)
#pragma unroll
                for (int r = 0; r < 4; ++r) {
                    float e = __expf(2.f * acc[mt][nt][r]);
                    rs[mt * 4 + r] += e;
                    cs[nt] += e;
                }
        if (J >= 32 && ((J - 32) >> 1) == I) {
            // tile contains the cross diagonal gcol == grow + 4096
#pragma unroll
            for (int mt = 0; mt < 4; ++mt)
#pragma unroll
                for (int nt = 0; nt < 4; ++nt) {
                    int gcol = n0 + wcol + nt * 16 + lane15;
#pragma unroll
                    for (int r = 0; r < 4; ++r) {
                        int grow = m0 + wrow + mt * 16 + quad * 4 + r;
                        if (gcol == grow + N_ROWS) {
                            float s = acc[mt][nt][r];
                            cdp[grow] = s;
                            cdp[gcol] = s;
                        }
                    }
                }
        }
    } else {
        // band tile: strict upper triangle only
#pragma unroll
        for (int mt = 0; mt < 4; ++mt)
#pragma unroll
            for (int nt = 0; nt < 4; ++nt) {
                int gcol = n0 + wcol + nt * 16 + lane15;
#pragma unroll
                for (int r = 0; r < 4; ++r) {
                    int grow = m0 + wrow + mt * 16 + quad * 4 + r;
                    if (grow < gcol) {
                        float e = __expf(2.f * acc[mt][nt][r]);
                        rs[mt * 4 + r] += e;
                        cs[nt] += e;
                    }
                }
            }
    }

#pragma unroll
    for (int j = 0; j < 16; ++j) {
        float v = rs[j];
        v += __shfl_xor(v, 1); v += __shfl_xor(v, 2);
        v += __shfl_xor(v, 4); v += __shfl_xor(v, 8);
        rs[j] = v;
    }
    if (lane15 == 0) {
#pragma unroll
        for (int j = 0; j < 16; ++j) {
            int grow = m0 + wrow + (j >> 2) * 16 + quad * 4 + (j & 3);
            atomicAdd(&rp[grow], rs[j]);
        }
    }
#pragma unroll
    for (int n = 0; n < 4; ++n) {
        float v = cs[n];
        v += __shfl_xor(v, 16); v += __shfl_xor(v, 32);
        cs[n] = v;
    }
    if (quad == 0) {
#pragma unroll
        for (int n = 0; n < 4; ++n) {
            int gcol = n0 + wcol + n * 16 + lane15;
            atomicAdd(&rp[gcol], cs[n]);
        }
    }
}

// ---------------- final loss reduction ----------------
__global__ void loss_kernel(const float* __restrict__ rowsum,
                            const float* __restrict__ crossdot, float* __restrict__ out) {
    __shared__ float red[256];
    float acc = 0.f;
    for (int i = threadIdx.x; i < 3 * 2 * N_ROWS; i += 256) {
        acc += logf(rowsum[i]) - 2.f * crossdot[i];
    }
    red[threadIdx.x] = acc;
    __syncthreads();
    for (int s = 128; s > 0; s >>= 1) {
        if (threadIdx.x < s) red[threadIdx.x] += red[threadIdx.x + s];
        __syncthreads();
    }
    if (threadIdx.x == 0) out[0] = red[0] * (1.f / 24576.f);
}

// ---------------- launch ----------------
extern "C" void kernel_launch(void* const* d_in, const int* in_sizes, int n_in,
                              void* d_out, int out_size, void* d_ws, size_t ws_size,
                              hipStream_t stream) {
    const float* doc0   = (const float*)d_in[0];
    const float* doc1   = (const float*)d_in[1];
    const float* doc2   = (const float*)d_in[2];
    const float* W1s    = (const float*)d_in[3];
    const float* b1s    = (const float*)d_in[4];
    const float* gammas = (const float*)d_in[5];
    const float* betas  = (const float*)d_in[6];
    const float* W2s    = (const float*)d_in[7];
    const float* b2s    = (const float*)d_in[8];
    float* out = (float*)d_out;

    char* base = (char*)d_ws;
    size_t off = 0;
    auto alloc = [&](size_t bytes) -> char* {
        char* r = base + off;
        off += (bytes + 255) & ~(size_t)255;
        return r;
    };

    unsigned short* Xb   = (unsigned short*)alloc((size_t)3 * N_ROWS * IN_DIM * 2);
    unsigned short* W1t  = (unsigned short*)alloc((size_t)6 * OUT_DIM * IN_DIM * 2);
    unsigned short* W2t  = (unsigned short*)alloc((size_t)6 * OUT_DIM * OUT_DIM * 2);
    float*          H    = (float*)         alloc((size_t)6 * N_ROWS * OUT_DIM * 4);
    unsigned short* Hb   = (unsigned short*)alloc((size_t)6 * N_ROWS * OUT_DIM * 2);
    unsigned char*  Abuf = (unsigned char*)Xb;    // Xb dead after gemm1
    unsigned short* O    = (unsigned short*)H;    // H dead after bn_apply
    char* zbase = alloc(24576 + 98304 + 98304);
    float* stats    = (float*)zbase;
    float* rowsumsq = (float*)(zbase + 24576);
    float* rowsum   = (float*)(zbase + 24576 + 98304);
    float* cdot     = (float*)alloc((size_t)3 * 2 * N_ROWS * 4);

    if (ws_size < off) return;

    prep<<<6582, 256, 0, stream>>>(doc0, doc1, doc2, W1s, W2s, Xb, W1t, W2t, zbase);

    gemm1_bn<<<dim3(OUT_DIM / 128, N_ROWS / 256, 6), 512, 0, stream>>>(Xb, W1t, b1s, H, stats);

    bn_apply<<<6144, 256, 0, stream>>>(H, Hb, stats, gammas, betas);

    gemm2_norm<<<dim3(OUT_DIM / 128, N_ROWS / 256, 6), 512, 0, stream>>>(Hb, W2t, b2s, O, rowsumsq);

    l2norm_fp8<<<1536, 256, 0, stream>>>(O, rowsumsq, Abuf);

    // supertile gram: 3 pairs x 1056 (J>=2I) tile-pairs, XCD swizzled
    gram_kernel<<<3168, 512, 0, stream>>>(Abuf, rowsum, cdot);

    loss_kernel<<<1, 256, 0, stream>>>(rowsum, cdot, out);
}